// Round 1
// baseline (413.761 us; speedup 1.0000x reference)
//
#include <hip/hip_runtime.h>

typedef short bf16x8 __attribute__((ext_vector_type(8)));
typedef unsigned short u16x8 __attribute__((ext_vector_type(8)));
typedef unsigned short u16x4 __attribute__((ext_vector_type(4)));
typedef float f32x4 __attribute__((ext_vector_type(4)));

#define DEV static __device__ __forceinline__

DEV float bf2f(unsigned short u) { return __uint_as_float(((unsigned)u) << 16); }
DEV unsigned short f2bf(float f) {
  unsigned u = __float_as_uint(f);
  return (unsigned short)((u + 0x7fffu + ((u >> 16) & 1u)) >> 16);
}

#define GLDS16(g, l)                                                                   \
  __builtin_amdgcn_global_load_lds((const __attribute__((address_space(1))) void*)(g), \
                                   (__attribute__((address_space(3))) void*)(l), 16, 0, 0)

// ---------------- fp32 -> bf16 convert with optional zero row-padding ----------------
__global__ __launch_bounds__(256) void convert_pad(const float* __restrict__ src,
                                                   unsigned short* __restrict__ dst,
                                                   int rows, int cols, int dstRows) {
  int i = blockIdx.x * 256 + threadIdx.x;
  int total4 = (dstRows * cols) >> 2;
  if (i >= total4) return;
  int e = i << 2;
  int r = e / cols;
  int c = e - r * cols;
  u16x4 o = {0, 0, 0, 0};
  if (r < rows) {
    const float* p = src + (size_t)r * cols + c;
    o[0] = f2bf(p[0]); o[1] = f2bf(p[1]); o[2] = f2bf(p[2]); o[3] = f2bf(p[3]);
  }
  *(u16x4*)(dst + e) = o;
}

// ---------------- bf16 GEMM: C[M,N] = A[M,K] @ B[N,K]^T  (m97 structure) ----------------
// 128x128 tile, BK=64, 4 waves (2x2), each wave 64x64 (4x4 frags of 16x16x32).
template <typename OutT>
__global__ __launch_bounds__(256, 2) void gemm_bt(const unsigned short* __restrict__ A,
                                                  const unsigned short* __restrict__ B,
                                                  OutT* __restrict__ C, int M, int N, int K) {
  __shared__ __align__(16) unsigned short As[128 * 64];
  __shared__ __align__(16) unsigned short Bs[128 * 64];
  const int tid = threadIdx.x;
  const int lane = tid & 63, wave = tid >> 6;
  const int l16 = lane & 15, lhi = lane >> 4;
  const int nbn = N >> 7;
  const int bm = blockIdx.x / nbn, bn = blockIdx.x - bm * nbn;
  const int m0 = bm << 7, n0 = bn << 7;
  const int wm = (wave >> 1) << 6, wn = (wave & 1) << 6;
  f32x4 acc[4][4] = {};
  for (int k0 = 0; k0 < K; k0 += 64) {
#pragma unroll
    for (int it = 0; it < 4; ++it) {
      int slot = it * 256 + tid;
      int row = slot >> 3, col = (slot & 7) << 3;  // 8 slots (64 bf16) per LDS row
      GLDS16(A + (size_t)(m0 + row) * K + k0 + col, As + (it * 256 + wave * 64) * 8);
      GLDS16(B + (size_t)(n0 + row) * K + k0 + col, Bs + (it * 256 + wave * 64) * 8);
    }
    __syncthreads();
#pragma unroll
    for (int ks = 0; ks < 2; ++ks) {
      bf16x8 a[4], b[4];
#pragma unroll
      for (int i = 0; i < 4; ++i) {
        a[i] = *(const bf16x8*)(As + (wm + i * 16 + l16) * 64 + ks * 32 + lhi * 8);
        b[i] = *(const bf16x8*)(Bs + (wn + i * 16 + l16) * 64 + ks * 32 + lhi * 8);
      }
#pragma unroll
      for (int i = 0; i < 4; ++i)
#pragma unroll
        for (int j = 0; j < 4; ++j)
          acc[i][j] = __builtin_amdgcn_mfma_f32_16x16x32_bf16(a[i], b[j], acc[i][j], 0, 0, 0);
    }
    __syncthreads();
  }
  // C/D layout: col = lane&15, row = (lane>>4)*4 + reg  [m89-verified]
#pragma unroll
  for (int i = 0; i < 4; ++i)
#pragma unroll
    for (int j = 0; j < 4; ++j)
#pragma unroll
      for (int r = 0; r < 4; ++r) {
        int row = m0 + wm + i * 16 + lhi * 4 + r;
        int col = n0 + wn + j * 16 + l16;
        float v = acc[i][j][r];
        if constexpr (sizeof(OutT) == 4)
          C[(size_t)row * N + col] = v;
        else
          C[(size_t)row * N + col] = (OutT)f2bf(v);
      }
}

// ---------------- RMS norm over 1536 cols (q path) ----------------
__global__ __launch_bounds__(256) void rms_q(const unsigned short* __restrict__ in,
                                             const float* __restrict__ w,
                                             unsigned short* __restrict__ out) {
  const int row = blockIdx.x, tid = threadIdx.x;
  const unsigned short* p = in + (size_t)row * 1536;
  float f[8];
  float ss = 0.f;
  const bool act = tid < 192;  // 192*8 = 1536
  if (act) {
    u16x8 v = *(const u16x8*)(p + tid * 8);
#pragma unroll
    for (int j = 0; j < 8; ++j) { f[j] = bf2f(v[j]); ss += f[j] * f[j]; }
  }
#pragma unroll
  for (int m = 1; m <= 32; m <<= 1) ss += __shfl_xor(ss, m);
  __shared__ float red[4];
  if ((tid & 63) == 0) red[tid >> 6] = ss;
  __syncthreads();
  float rstd = rsqrtf((red[0] + red[1] + red[2] + red[3]) * (1.f / 1536.f) + 1e-6f);
  if (act) {
    u16x8 o;
#pragma unroll
    for (int j = 0; j < 8; ++j) o[j] = f2bf(f[j] * rstd * w[tid * 8 + j]);
    *(u16x8*)(out + (size_t)row * 1536 + tid * 8) = o;
  }
}

// ---------------- RMS norm over 512 cols + RoPE on cols 512..575 (kv path) ----------------
__global__ __launch_bounds__(256) void rms_kv(const unsigned short* __restrict__ kva,  // [4096][640]
                                              const float* __restrict__ w,
                                              unsigned short* __restrict__ kvc,    // [4096][512]
                                              unsigned short* __restrict__ krope)  // [4096][64]
{
  const int row = blockIdx.x, tid = threadIdx.x;
  const unsigned short* p = kva + (size_t)row * 640;
  float f0 = bf2f(p[tid * 2]), f1 = bf2f(p[tid * 2 + 1]);
  float ss = f0 * f0 + f1 * f1;
#pragma unroll
  for (int m = 1; m <= 32; m <<= 1) ss += __shfl_xor(ss, m);
  __shared__ float red[4];
  if ((tid & 63) == 0) red[tid >> 6] = ss;
  __syncthreads();
  float rstd = rsqrtf((red[0] + red[1] + red[2] + red[3]) * (1.f / 512.f) + 1e-6f);
  kvc[(size_t)row * 512 + tid * 2]     = f2bf(f0 * rstd * w[tid * 2]);
  kvc[(size_t)row * 512 + tid * 2 + 1] = f2bf(f1 * rstd * w[tid * 2 + 1]);
  if (tid < 32) {
    int j = tid;
    float xr = bf2f(p[512 + 2 * j]), xi = bf2f(p[512 + 2 * j + 1]);
    int t = row & 2047;
    float ang = (float)t * powf(10000.f, -(float)j * (1.f / 32.f));
    float c = cosf(ang), s = sinf(ang);
    krope[(size_t)row * 64 + 2 * j]     = f2bf(xr * c - xi * s);
    krope[(size_t)row * 64 + 2 * j + 1] = f2bf(xr * s + xi * c);
  }
}

// ---------------- assemble K,V in [B][H][T][128] from kv_full + krope ----------------
__global__ __launch_bounds__(256) void kv_asm(const unsigned short* __restrict__ kvfull,  // [4096][3072]
                                              const unsigned short* __restrict__ krope,   // [4096][64]
                                              unsigned short* __restrict__ K,
                                              unsigned short* __restrict__ V) {
  int i = blockIdx.x * 256 + threadIdx.x;
  if (i >= 2 * 2048 * 16 * 128) return;
  int d = i & 127, h = (i >> 7) & 15, tl = i >> 11;
  int b = tl >> 11, t = tl & 2047;
  size_t oidx = ((size_t)((b * 16 + h) * 2048 + t)) * 128 + d;
  K[oidx] = (d < 64) ? kvfull[(size_t)tl * 3072 + h * 192 + d] : krope[(size_t)tl * 64 + d - 64];
  V[oidx] = kvfull[(size_t)tl * 3072 + h * 192 + 64 + d];
}

// ---------------- causal flash attention ----------------
// grid = (T/128) * H * B; 4 waves; each wave: 32 q-rows. KBLK=64, D=128.
// Q read straight from q_full (RoPE + 0.125 scale applied at load).
__global__ __launch_bounds__(256, 2) void flash_attn(const unsigned short* __restrict__ qfull,  // [4096][2048]
                                                     const unsigned short* __restrict__ Kt,     // [B][H][T][128]
                                                     const unsigned short* __restrict__ Vt,
                                                     unsigned short* __restrict__ out)          // [4096][2048]
{
  const int tid = threadIdx.x, lane = tid & 63, wave = tid >> 6;
  const int l16 = lane & 15, lhi = lane >> 4;
  const int qb = blockIdx.x & 15;
  const int h = (blockIdx.x >> 4) & 15;
  const int b = blockIdx.x >> 8;
  const int q0 = qb * 128;
  __shared__ __align__(16) unsigned short Ks[64 * 136];   // [kvrow][d], +8 pad
  __shared__ __align__(16) unsigned short Vs[128 * 72];   // transposed: [d][kvrow], +8 pad
  __shared__ __align__(16) unsigned short Ps[4][32 * 72]; // per-wave P, +8 pad

  // --- load Q fragments, apply RoPE to d>=64 and fold in softmax scale 1/8 ---
  bf16x8 qf[2][4];
  float m_run[2][4], l_run[2][4];
  f32x4 o_acc[2][8] = {};
#pragma unroll
  for (int mt = 0; mt < 2; ++mt) {
    int t = q0 + wave * 32 + mt * 16 + l16;
    const unsigned short* qrow = qfull + (size_t)(b * 2048 + t) * 2048 + h * 128;
#pragma unroll
    for (int ks = 0; ks < 4; ++ks) {
      u16x8 raw = *(const u16x8*)(qrow + ks * 32 + lhi * 8);
      float f[8];
#pragma unroll
      for (int j = 0; j < 8; ++j) f[j] = bf2f(raw[j]);
      if (ks >= 2) {
#pragma unroll
        for (int pp = 0; pp < 4; ++pp) {
          int d = ks * 32 + lhi * 8 + 2 * pp;
          int jl = (d - 64) >> 1;
          float ang = (float)t * powf(10000.f, -(float)jl * (1.f / 32.f));
          float c = cosf(ang), s = sinf(ang);
          float xr = f[2 * pp], xi = f[2 * pp + 1];
          f[2 * pp] = xr * c - xi * s;
          f[2 * pp + 1] = xr * s + xi * c;
        }
      }
      bf16x8 fr;
#pragma unroll
      for (int j = 0; j < 8; ++j) fr[j] = (short)f2bf(f[j] * 0.125f);
      qf[mt][ks] = fr;
    }
#pragma unroll
    for (int r = 0; r < 4; ++r) { m_run[mt][r] = -1e30f; l_run[mt][r] = 0.f; }
  }

  const unsigned short* Kbase = Kt + ((size_t)(b * 16 + h)) * 2048 * 128;
  const unsigned short* Vbase = Vt + ((size_t)(b * 16 + h)) * 2048 * 128;
  const int ntiles = qb * 2 + 2;

  for (int kt = 0; kt < ntiles; ++kt) {
    const int t0 = kt * 64;
    __syncthreads();  // staging vs previous tile's reads
    // stage K [64][128] -> Ks (coalesced, conflict-free)
#pragma unroll
    for (int it = 0; it < 4; ++it) {
      int slot = it * 256 + tid;
      int row = slot >> 4, col = (slot & 15) << 3;
      u16x8 v = *(const u16x8*)(Kbase + (size_t)(t0 + row) * 128 + col);
      *(u16x8*)(Ks + row * 136 + col) = v;
    }
    // stage V transposed: lane owns kv-row r, scatter-writes are LDS-contiguous across lanes
    {
      int r = tid & 63, w4 = tid >> 6;
#pragma unroll
      for (int it = 0; it < 4; ++it) {
        int c = w4 * 8 + it * 32;
        u16x8 v = *(const u16x8*)(Vbase + (size_t)(t0 + r) * 128 + c);
#pragma unroll
        for (int j = 0; j < 8; ++j) Vs[(c + j) * 72 + r] = v[j];
      }
    }
    __syncthreads();

    // --- S = Q @ K^T ---
    f32x4 sacc[2][4] = {};
#pragma unroll
    for (int ks = 0; ks < 4; ++ks) {
      bf16x8 kf[4];
#pragma unroll
      for (int nt = 0; nt < 4; ++nt)
        kf[nt] = *(const bf16x8*)(Ks + (nt * 16 + l16) * 136 + ks * 32 + lhi * 8);
#pragma unroll
      for (int mt = 0; mt < 2; ++mt)
#pragma unroll
        for (int nt = 0; nt < 4; ++nt)
          sacc[mt][nt] = __builtin_amdgcn_mfma_f32_16x16x32_bf16(qf[mt][ks], kf[nt], sacc[mt][nt], 0, 0, 0);
    }

    // --- mask + online softmax (per wave, rows mt*16 + lhi*4 + r) ---
#pragma unroll
    for (int mt = 0; mt < 2; ++mt) {
      int mrow = q0 + wave * 32 + mt * 16 + lhi * 4;
      float rmax[4], rsum[4], scale[4], mnew[4];
#pragma unroll
      for (int r = 0; r < 4; ++r) rmax[r] = -1e30f;
#pragma unroll
      for (int nt = 0; nt < 4; ++nt) {
        int ncol = t0 + nt * 16 + l16;
#pragma unroll
        for (int r = 0; r < 4; ++r) {
          float s = sacc[mt][nt][r];
          s = (ncol <= mrow + r) ? s : -1e30f;
          sacc[mt][nt][r] = s;
          rmax[r] = fmaxf(rmax[r], s);
        }
      }
#pragma unroll
      for (int m = 1; m <= 8; m <<= 1)
#pragma unroll
        for (int r = 0; r < 4; ++r) rmax[r] = fmaxf(rmax[r], __shfl_xor(rmax[r], m));
#pragma unroll
      for (int r = 0; r < 4; ++r) {
        mnew[r] = fmaxf(m_run[mt][r], rmax[r]);
        scale[r] = __expf(m_run[mt][r] - mnew[r]);
        m_run[mt][r] = mnew[r];
        rsum[r] = 0.f;
      }
#pragma unroll
      for (int nt = 0; nt < 4; ++nt)
#pragma unroll
        for (int r = 0; r < 4; ++r) {
          float pv = __expf(sacc[mt][nt][r] - mnew[r]);
          sacc[mt][nt][r] = pv;
          rsum[r] += pv;
        }
#pragma unroll
      for (int m = 1; m <= 8; m <<= 1)
#pragma unroll
        for (int r = 0; r < 4; ++r) rsum[r] += __shfl_xor(rsum[r], m);
#pragma unroll
      for (int r = 0; r < 4; ++r) l_run[mt][r] = l_run[mt][r] * scale[r] + rsum[r];
#pragma unroll
      for (int dt = 0; dt < 8; ++dt)
#pragma unroll
        for (int r = 0; r < 4; ++r) o_acc[mt][dt][r] *= scale[r];
      // write P (bf16) to per-wave LDS in D-layout
#pragma unroll
      for (int nt = 0; nt < 4; ++nt)
#pragma unroll
        for (int r = 0; r < 4; ++r)
          Ps[wave][(mt * 16 + lhi * 4 + r) * 72 + nt * 16 + l16] = f2bf(sacc[mt][nt][r]);
    }
    __syncthreads();  // safety: P visible before PV reads (also orders vs Vs)

    // --- O += P @ V ---
#pragma unroll
    for (int ks = 0; ks < 2; ++ks) {
      bf16x8 pf[2];
#pragma unroll
      for (int mt = 0; mt < 2; ++mt)
        pf[mt] = *(const bf16x8*)(&Ps[wave][(mt * 16 + l16) * 72 + ks * 32 + lhi * 8]);
#pragma unroll
      for (int dt = 0; dt < 8; ++dt) {
        bf16x8 vf = *(const bf16x8*)(Vs + (dt * 16 + l16) * 72 + ks * 32 + lhi * 8);
#pragma unroll
        for (int mt = 0; mt < 2; ++mt)
          o_acc[mt][dt] = __builtin_amdgcn_mfma_f32_16x16x32_bf16(pf[mt], vf, o_acc[mt][dt], 0, 0, 0);
      }
    }
  }

  // --- epilogue: out[t][h*128+d] = O / l ---
#pragma unroll
  for (int mt = 0; mt < 2; ++mt)
#pragma unroll
    for (int r = 0; r < 4; ++r) {
      int t = q0 + wave * 32 + mt * 16 + lhi * 4 + r;
      float inv_l = 1.0f / l_run[mt][r];
      unsigned short* orow = out + (size_t)(b * 2048 + t) * 2048 + h * 128;
#pragma unroll
      for (int dt = 0; dt < 8; ++dt) orow[dt * 16 + l16] = f2bf(o_acc[mt][dt][r] * inv_l);
    }
}

// =====================================================================================
extern "C" void kernel_launch(void* const* d_in, const int* in_sizes, int n_in,
                              void* d_out, int out_size, void* d_ws, size_t ws_size,
                              hipStream_t stream) {
  (void)in_sizes; (void)n_in; (void)out_size; (void)ws_size;
  const float* x      = (const float*)d_in[0];
  // d_in[1] = mask (causal tril) — implied by kernel structure
  const float* w_qa   = (const float*)d_in[2];
  const float* qa_nw  = (const float*)d_in[3];
  const float* w_qb   = (const float*)d_in[4];
  const float* w_kva  = (const float*)d_in[5];
  const float* kva_nw = (const float*)d_in[6];
  const float* w_kvb  = (const float*)d_in[7];
  const float* w_o    = (const float*)d_in[8];
  float* out = (float*)d_out;
  char* ws = (char*)d_ws;

  // ---- workspace layout (bytes); aliasing is liveness-checked ----
  unsigned short* xb     = (unsigned short*)(ws + 0);          // 16.78 MB, dead after GEMM2 -> reused as Kattn
  unsigned short* wqab   = (unsigned short*)(ws + 16777216);
  unsigned short* wqbb   = (unsigned short*)(ws + 23068672);
  unsigned short* wkvab  = (unsigned short*)(ws + 29360128);   // padded to 640 rows
  unsigned short* wkvbb  = (unsigned short*)(ws + 31981568);
  unsigned short* wob    = (unsigned short*)(ws + 35127296);
  unsigned short* q_a    = (unsigned short*)(ws + 43515904);   // [4096][1536]
  unsigned short* kv_a   = (unsigned short*)(ws + 56098816);   // [4096][640]
  unsigned short* qfull  = (unsigned short*)(ws + 43515904);   // [4096][2048] over q_a+kv_a (both dead)
  unsigned short* q_c    = (unsigned short*)(ws + 61341696);   // [4096][1536]
  unsigned short* kv_c   = (unsigned short*)(ws + 73924608);   // [4096][512]
  unsigned short* krope  = (unsigned short*)(ws + 78118912);   // [4096][64]
  unsigned short* attno  = (unsigned short*)(ws + 61341696);   // [4096][2048] over q_c+kv_c (both dead)
  unsigned short* Vattn  = (unsigned short*)(ws + 78643200);   // [B][H][T][128]
  unsigned short* Kattn  = xb;                                  // reuse
  unsigned short* kvfull = (unsigned short*)d_out;              // [4096][3072] scratch in d_out (25.2<33.5MB)

  // 1) converts
  convert_pad<<<8192, 256, 0, stream>>>(x,     xb,    4096, 2048, 4096);
  convert_pad<<<3072, 256, 0, stream>>>(w_qa,  wqab,  1536, 2048, 1536);
  convert_pad<<<3072, 256, 0, stream>>>(w_qb,  wqbb,  2048, 1536, 2048);
  convert_pad<<<1280, 256, 0, stream>>>(w_kva, wkvab,  576, 2048,  640);
  convert_pad<<<1536, 256, 0, stream>>>(w_kvb, wkvbb, 3072,  512, 3072);
  convert_pad<<<4096, 256, 0, stream>>>(w_o,   wob,   2048, 2048, 2048);

  // 2) low-rank projections
  gemm_bt<unsigned short><<<32 * 12, 256, 0, stream>>>(xb, wqab,  q_a,  4096, 1536, 2048);
  gemm_bt<unsigned short><<<32 * 5,  256, 0, stream>>>(xb, wkvab, kv_a, 4096,  640, 2048);

  // 3) norms (+ RoPE of shared k_rope)
  rms_q<<<4096, 256, 0, stream>>>(q_a, qa_nw, q_c);
  rms_kv<<<4096, 256, 0, stream>>>(kv_a, kva_nw, kv_c, krope);

  // 4) up-projections
  gemm_bt<unsigned short><<<32 * 16, 256, 0, stream>>>(q_c,  wqbb,  qfull,  4096, 2048, 1536);
  gemm_bt<unsigned short><<<32 * 24, 256, 0, stream>>>(kv_c, wkvbb, kvfull, 4096, 3072,  512);

  // 5) K/V assembly into [B][H][T][128]
  kv_asm<<<32768, 256, 0, stream>>>(kvfull, krope, Kattn, Vattn);

  // 6) causal flash attention (RoPE+scale on Q applied in-kernel)
  flash_attn<<<512, 256, 0, stream>>>(qfull, Kattn, Vattn, attno);

  // 7) output projection (fp32 out)
  gemm_bt<float><<<32 * 16, 256, 0, stream>>>(attno, wob, out, 4096, 2048, 2048);
}

// Round 2
// 357.514 us; speedup vs baseline: 1.1573x; 1.1573x over previous
//
#include <hip/hip_runtime.h>

typedef short bf16x8 __attribute__((ext_vector_type(8)));
typedef unsigned short u16x8 __attribute__((ext_vector_type(8)));
typedef unsigned short u16x4 __attribute__((ext_vector_type(4)));
typedef float f32x4 __attribute__((ext_vector_type(4)));

#define DEV static __device__ __forceinline__

DEV float bf2f(unsigned short u) { return __uint_as_float(((unsigned)u) << 16); }
DEV unsigned short f2bf(float f) {
  unsigned u = __float_as_uint(f);
  return (unsigned short)((u + 0x7fffu + ((u >> 16) & 1u)) >> 16);
}

#define GLDS16(g, l)                                                                   \
  __builtin_amdgcn_global_load_lds((const __attribute__((address_space(1))) void*)(g), \
                                   (__attribute__((address_space(3))) void*)(l), 16, 0, 0)

// ---------------- fp32 -> bf16 convert with optional zero row-padding ----------------
__global__ __launch_bounds__(256) void convert_pad(const float* __restrict__ src,
                                                   unsigned short* __restrict__ dst,
                                                   int rows, int cols, int dstRows) {
  int i = blockIdx.x * 256 + threadIdx.x;
  int total4 = (dstRows * cols) >> 2;
  if (i >= total4) return;
  int e = i << 2;
  int r = e / cols;
  int c = e - r * cols;
  u16x4 o = {0, 0, 0, 0};
  if (r < rows) {
    const float* p = src + (size_t)r * cols + c;
    o[0] = f2bf(p[0]); o[1] = f2bf(p[1]); o[2] = f2bf(p[2]); o[3] = f2bf(p[3]);
  }
  *(u16x4*)(dst + e) = o;
}

// ---------------- bf16 GEMM: C[M,N] = A[M,K] @ B[N,K]^T  (m97 structure) ----------------
template <typename OutT>
__global__ __launch_bounds__(256, 2) void gemm_bt(const unsigned short* __restrict__ A,
                                                  const unsigned short* __restrict__ B,
                                                  OutT* __restrict__ C, int M, int N, int K) {
  __shared__ __align__(16) unsigned short As[128 * 64];
  __shared__ __align__(16) unsigned short Bs[128 * 64];
  const int tid = threadIdx.x;
  const int lane = tid & 63, wave = tid >> 6;
  const int l16 = lane & 15, lhi = lane >> 4;
  const int nbn = N >> 7;
  const int bm = blockIdx.x / nbn, bn = blockIdx.x - bm * nbn;
  const int m0 = bm << 7, n0 = bn << 7;
  const int wm = (wave >> 1) << 6, wn = (wave & 1) << 6;
  f32x4 acc[4][4] = {};
  for (int k0 = 0; k0 < K; k0 += 64) {
#pragma unroll
    for (int it = 0; it < 4; ++it) {
      int slot = it * 256 + tid;
      int row = slot >> 3, col = (slot & 7) << 3;
      GLDS16(A + (size_t)(m0 + row) * K + k0 + col, As + (it * 256 + wave * 64) * 8);
      GLDS16(B + (size_t)(n0 + row) * K + k0 + col, Bs + (it * 256 + wave * 64) * 8);
    }
    __syncthreads();
#pragma unroll
    for (int ks = 0; ks < 2; ++ks) {
      bf16x8 a[4], b[4];
#pragma unroll
      for (int i = 0; i < 4; ++i) {
        a[i] = *(const bf16x8*)(As + (wm + i * 16 + l16) * 64 + ks * 32 + lhi * 8);
        b[i] = *(const bf16x8*)(Bs + (wn + i * 16 + l16) * 64 + ks * 32 + lhi * 8);
      }
#pragma unroll
      for (int i = 0; i < 4; ++i)
#pragma unroll
        for (int j = 0; j < 4; ++j)
          acc[i][j] = __builtin_amdgcn_mfma_f32_16x16x32_bf16(a[i], b[j], acc[i][j], 0, 0, 0);
    }
    __syncthreads();
  }
#pragma unroll
  for (int i = 0; i < 4; ++i)
#pragma unroll
    for (int j = 0; j < 4; ++j)
#pragma unroll
      for (int r = 0; r < 4; ++r) {
        int row = m0 + wm + i * 16 + lhi * 4 + r;
        int col = n0 + wn + j * 16 + l16;
        float v = acc[i][j][r];
        if constexpr (sizeof(OutT) == 4)
          C[(size_t)row * N + col] = v;
        else
          C[(size_t)row * N + col] = (OutT)f2bf(v);
      }
}

// ---------------- RMS norm over 1536 cols (q path) ----------------
__global__ __launch_bounds__(256) void rms_q(const unsigned short* __restrict__ in,
                                             const float* __restrict__ w,
                                             unsigned short* __restrict__ out) {
  const int row = blockIdx.x, tid = threadIdx.x;
  const unsigned short* p = in + (size_t)row * 1536;
  float f[8];
  float ss = 0.f;
  const bool act = tid < 192;
  if (act) {
    u16x8 v = *(const u16x8*)(p + tid * 8);
#pragma unroll
    for (int j = 0; j < 8; ++j) { f[j] = bf2f(v[j]); ss += f[j] * f[j]; }
  }
#pragma unroll
  for (int m = 1; m <= 32; m <<= 1) ss += __shfl_xor(ss, m);
  __shared__ float red[4];
  if ((tid & 63) == 0) red[tid >> 6] = ss;
  __syncthreads();
  float rstd = rsqrtf((red[0] + red[1] + red[2] + red[3]) * (1.f / 1536.f) + 1e-6f);
  if (act) {
    u16x8 o;
#pragma unroll
    for (int j = 0; j < 8; ++j) o[j] = f2bf(f[j] * rstd * w[tid * 8 + j]);
    *(u16x8*)(out + (size_t)row * 1536 + tid * 8) = o;
  }
}

// ---------------- RMS norm over 512 cols + RoPE on cols 512..575 (kv path) ----------------
__global__ __launch_bounds__(256) void rms_kv(const unsigned short* __restrict__ kva,
                                              const float* __restrict__ w,
                                              unsigned short* __restrict__ kvc,
                                              unsigned short* __restrict__ krope) {
  const int row = blockIdx.x, tid = threadIdx.x;
  const unsigned short* p = kva + (size_t)row * 640;
  float f0 = bf2f(p[tid * 2]), f1 = bf2f(p[tid * 2 + 1]);
  float ss = f0 * f0 + f1 * f1;
#pragma unroll
  for (int m = 1; m <= 32; m <<= 1) ss += __shfl_xor(ss, m);
  __shared__ float red[4];
  if ((tid & 63) == 0) red[tid >> 6] = ss;
  __syncthreads();
  float rstd = rsqrtf((red[0] + red[1] + red[2] + red[3]) * (1.f / 512.f) + 1e-6f);
  kvc[(size_t)row * 512 + tid * 2]     = f2bf(f0 * rstd * w[tid * 2]);
  kvc[(size_t)row * 512 + tid * 2 + 1] = f2bf(f1 * rstd * w[tid * 2 + 1]);
  if (tid < 32) {
    int j = tid;
    float xr = bf2f(p[512 + 2 * j]), xi = bf2f(p[512 + 2 * j + 1]);
    int t = row & 2047;
    float ang = (float)t * powf(10000.f, -(float)j * (1.f / 32.f));
    float c = cosf(ang), s = sinf(ang);
    krope[(size_t)row * 64 + 2 * j]     = f2bf(xr * c - xi * s);
    krope[(size_t)row * 64 + 2 * j + 1] = f2bf(xr * s + xi * c);
  }
}

// ---------------- assemble K in [B][H][T][128] from kv_full + krope ----------------
__global__ __launch_bounds__(256) void kv_asm_k(const unsigned short* __restrict__ kvfull,
                                                const unsigned short* __restrict__ krope,
                                                unsigned short* __restrict__ K) {
  int i = blockIdx.x * 256 + threadIdx.x;
  if (i >= 2 * 2048 * 16 * 128) return;
  int d = i & 127, h = (i >> 7) & 15, tl = i >> 11;
  int b = tl >> 11, t = tl & 2047;
  size_t oidx = ((size_t)((b * 16 + h) * 2048 + t)) * 128 + d;
  K[oidx] = (d < 64) ? kvfull[(size_t)tl * 3072 + h * 192 + d] : krope[(size_t)tl * 64 + d - 64];
}

// ---------------- V^T materialization: VT[b][h][d][t] = kvfull[b,t][h*192+64+d] ----------------
__global__ __launch_bounds__(256) void v_transpose(const unsigned short* __restrict__ kvfull,
                                                   unsigned short* __restrict__ VT) {
  __shared__ unsigned short tile[64][137];
  const int tid = threadIdx.x;
  const int tt = blockIdx.x & 31, h = (blockIdx.x >> 5) & 15, b = blockIdx.x >> 9;
  const int t0 = tt * 64;
#pragma unroll
  for (int it = 0; it < 4; ++it) {
    int s = it * 256 + tid;
    int r = s >> 4, c = (s & 15) << 3;
    u16x8 v = *(const u16x8*)(kvfull + (size_t)(b * 2048 + t0 + r) * 3072 + h * 192 + 64 + c);
    *(u16x8*)(&tile[r][c]) = v;
  }
  __syncthreads();
#pragma unroll
  for (int it = 0; it < 4; ++it) {
    int s = it * 256 + tid;
    int d = s >> 3, tc = (s & 7) << 3;
    u16x8 o;
#pragma unroll
    for (int j = 0; j < 8; ++j) o[j] = tile[tc + j][d];
    *(u16x8*)(VT + ((size_t)(b * 16 + h) * 128 + d) * 2048 + t0 + tc) = o;
  }
}

// ---------------- causal flash attention, balanced pairing ----------------
// Block = (pair pr, h, b). Sub-blocks sA=pr, sB=31-pr (64 q-rows each) -> every block
// does exactly 33 mt-tile-units. 4 waves; wave owns 16 rows of each sub-block.
// K staged [64][128] and V^T staged [128][64] via global_load_lds with XOR-swizzle
// (linear LDS dest + inverse-swizzled per-lane global src + swizzled ds_read).
__global__ __launch_bounds__(256, 2) void flash_attn(const unsigned short* __restrict__ qfull,
                                                     const unsigned short* __restrict__ Kt,  // [B][H][2048][128]
                                                     const unsigned short* __restrict__ Vt,  // [B][H][128][2048]
                                                     unsigned short* __restrict__ out) {
  const int tid = threadIdx.x, lane = tid & 63, wave = tid >> 6;
  const int l16 = lane & 15, lhi = lane >> 4;
  const int pr = blockIdx.x & 15;
  const int h = (blockIdx.x >> 4) & 15;
  const int b = blockIdx.x >> 8;
  const int sA = pr, sB = 31 - pr;
  __shared__ __align__(16) unsigned short Ks[64 * 128];   // [kv][d] rows 256B, XOR-swizzled
  __shared__ __align__(16) unsigned short Vs[128 * 64];   // [d][kv] rows 128B, XOR-swizzled
  __shared__ __align__(16) unsigned short Ps[4][16 * 88]; // per-wave P, stride 176B (16B-aligned)

  bf16x8 qf[2][4];
  float m_run[2][4], l_run[2][4];
  f32x4 o_acc[2][8] = {};
#pragma unroll
  for (int u = 0; u < 2; ++u) {
    const int s_u = u ? sB : sA;
    int t = s_u * 64 + wave * 16 + l16;
    const unsigned short* qrow = qfull + (size_t)(b * 2048 + t) * 2048 + h * 128;
#pragma unroll
    for (int ks = 0; ks < 4; ++ks) {
      u16x8 raw = *(const u16x8*)(qrow + ks * 32 + lhi * 8);
      float f[8];
#pragma unroll
      for (int j = 0; j < 8; ++j) f[j] = bf2f(raw[j]);
      if (ks >= 2) {
#pragma unroll
        for (int pp = 0; pp < 4; ++pp) {
          int d = ks * 32 + lhi * 8 + 2 * pp;
          int jl = (d - 64) >> 1;
          float ang = (float)t * powf(10000.f, -(float)jl * (1.f / 32.f));
          float c = cosf(ang), s = sinf(ang);
          float xr = f[2 * pp], xi = f[2 * pp + 1];
          f[2 * pp] = xr * c - xi * s;
          f[2 * pp + 1] = xr * s + xi * c;
        }
      }
      bf16x8 fr;
#pragma unroll
      for (int j = 0; j < 8; ++j) fr[j] = (short)f2bf(f[j] * 0.125f);
      qf[u][ks] = fr;
    }
#pragma unroll
    for (int r = 0; r < 4; ++r) { m_run[u][r] = -1e30f; l_run[u][r] = 0.f; }
  }

  const unsigned short* Kbh = Kt + (size_t)(b * 16 + h) * 2048 * 128;
  const unsigned short* Vbh = Vt + (size_t)(b * 16 + h) * 128 * 2048;

  for (int kt = 0; kt <= sB; ++kt) {
    const int t0 = kt * 64;
    const bool actA = (kt <= sA);
    __syncthreads();  // prev tile's reads done before overwrite
    // stage K tile [64 kv][128 d]: 4 rounds x (4 waves x 1KB)
#pragma unroll
    for (int it = 0; it < 4; ++it) {
      int L = it * 4096 + wave * 1024 + lane * 16;
      int r = L >> 8;
      int w = (L & 255) ^ ((r & 7) << 4);
      GLDS16(Kbh + (size_t)(t0 + r) * 128 + (w >> 1), Ks + ((it * 4096 + wave * 1024) >> 1));
    }
    // stage V^T tile [128 d][64 kv]
#pragma unroll
    for (int it = 0; it < 4; ++it) {
      int L = it * 4096 + wave * 1024 + lane * 16;
      int d = L >> 7;
      int w = (L & 127) ^ ((d & 7) << 4);
      GLDS16(Vbh + (size_t)d * 2048 + t0 + (w >> 1), Vs + ((it * 4096 + wave * 1024) >> 1));
    }
    __syncthreads();  // drains vmcnt (compiler emits before barrier)

    // --- S = Q @ K^T for active sub-blocks ---
    f32x4 sacc[2][4] = {};
#pragma unroll
    for (int ks = 0; ks < 4; ++ks) {
      bf16x8 kf[4];
#pragma unroll
      for (int nt = 0; nt < 4; ++nt) {
        int row = nt * 16 + l16;
        int byteoff = row * 256 + ((ks * 64 + lhi * 16) ^ ((l16 & 7) << 4));
        kf[nt] = *(const bf16x8*)((const char*)Ks + byteoff);
      }
#pragma unroll
      for (int u = 0; u < 2; ++u) {
        if (u == 0 && !actA) continue;
#pragma unroll
        for (int nt = 0; nt < 4; ++nt)
          sacc[u][nt] = __builtin_amdgcn_mfma_f32_16x16x32_bf16(qf[u][ks], kf[nt], sacc[u][nt], 0, 0, 0);
      }
    }

    // --- softmax + PV per active sub-block ---
#pragma unroll
    for (int u = 0; u < 2; ++u) {
      if (u == 0 && !actA) continue;
      const int s_u = u ? sB : sA;
      const int mrow = s_u * 64 + wave * 16 + lhi * 4;
      float rmax[4], rsum[4], scale[4], mnew[4];
#pragma unroll
      for (int r = 0; r < 4; ++r) rmax[r] = -1e30f;
      if (kt == s_u) {  // diagonal tile: apply causal mask
#pragma unroll
        for (int nt = 0; nt < 4; ++nt) {
          int ncol = t0 + nt * 16 + l16;
#pragma unroll
          for (int r = 0; r < 4; ++r) {
            float s = sacc[u][nt][r];
            s = (ncol <= mrow + r) ? s : -1e30f;
            sacc[u][nt][r] = s;
            rmax[r] = fmaxf(rmax[r], s);
          }
        }
      } else {
#pragma unroll
        for (int nt = 0; nt < 4; ++nt)
#pragma unroll
          for (int r = 0; r < 4; ++r) rmax[r] = fmaxf(rmax[r], sacc[u][nt][r]);
      }
#pragma unroll
      for (int m = 1; m <= 8; m <<= 1)
#pragma unroll
        for (int r = 0; r < 4; ++r) rmax[r] = fmaxf(rmax[r], __shfl_xor(rmax[r], m));
#pragma unroll
      for (int r = 0; r < 4; ++r) {
        mnew[r] = fmaxf(m_run[u][r], rmax[r]);
        scale[r] = __expf(m_run[u][r] - mnew[r]);
        m_run[u][r] = mnew[r];
        rsum[r] = 0.f;
      }
#pragma unroll
      for (int nt = 0; nt < 4; ++nt)
#pragma unroll
        for (int r = 0; r < 4; ++r) {
          float pv = __expf(sacc[u][nt][r] - mnew[r]);
          sacc[u][nt][r] = pv;
          rsum[r] += pv;
        }
#pragma unroll
      for (int m = 1; m <= 8; m <<= 1)
#pragma unroll
        for (int r = 0; r < 4; ++r) rsum[r] += __shfl_xor(rsum[r], m);
#pragma unroll
      for (int r = 0; r < 4; ++r) l_run[u][r] = l_run[u][r] * scale[r] + rsum[r];
#pragma unroll
      for (int dt = 0; dt < 8; ++dt)
#pragma unroll
        for (int r = 0; r < 4; ++r) o_acc[u][dt][r] *= scale[r];
#pragma unroll
      for (int nt = 0; nt < 4; ++nt)
#pragma unroll
        for (int r = 0; r < 4; ++r)
          Ps[wave][(lhi * 4 + r) * 88 + nt * 16 + l16] = f2bf(sacc[u][nt][r]);
      // PV for this sub-block (wave-local: compiler inserts lgkmcnt between write/read)
#pragma unroll
      for (int ks = 0; ks < 2; ++ks) {
        bf16x8 pf = *(const bf16x8*)(&Ps[wave][l16 * 88 + ks * 32 + lhi * 8]);
#pragma unroll
        for (int dt = 0; dt < 8; ++dt) {
          int row = dt * 16 + l16;
          int byteoff = row * 128 + ((ks * 64 + lhi * 16) ^ ((l16 & 7) << 4));
          bf16x8 vf = *(const bf16x8*)((const char*)Vs + byteoff);
          o_acc[u][dt] = __builtin_amdgcn_mfma_f32_16x16x32_bf16(pf, vf, o_acc[u][dt], 0, 0, 0);
        }
      }
    }
  }

  // --- epilogue ---
#pragma unroll
  for (int u = 0; u < 2; ++u) {
    const int s_u = u ? sB : sA;
#pragma unroll
    for (int r = 0; r < 4; ++r) {
      int t = s_u * 64 + wave * 16 + lhi * 4 + r;
      float inv_l = 1.0f / l_run[u][r];
      unsigned short* orow = out + (size_t)(b * 2048 + t) * 2048 + h * 128;
#pragma unroll
      for (int dt = 0; dt < 8; ++dt) orow[dt * 16 + l16] = f2bf(o_acc[u][dt][r] * inv_l);
    }
  }
}

// =====================================================================================
extern "C" void kernel_launch(void* const* d_in, const int* in_sizes, int n_in,
                              void* d_out, int out_size, void* d_ws, size_t ws_size,
                              hipStream_t stream) {
  (void)in_sizes; (void)n_in; (void)out_size; (void)ws_size;
  const float* x      = (const float*)d_in[0];
  const float* w_qa   = (const float*)d_in[2];
  const float* qa_nw  = (const float*)d_in[3];
  const float* w_qb   = (const float*)d_in[4];
  const float* w_kva  = (const float*)d_in[5];
  const float* kva_nw = (const float*)d_in[6];
  const float* w_kvb  = (const float*)d_in[7];
  const float* w_o    = (const float*)d_in[8];
  float* out = (float*)d_out;
  char* ws = (char*)d_ws;

  unsigned short* xb     = (unsigned short*)(ws + 0);          // dead after GEMM1/2 -> Kattn
  unsigned short* wqab   = (unsigned short*)(ws + 16777216);
  unsigned short* wqbb   = (unsigned short*)(ws + 23068672);
  unsigned short* wkvab  = (unsigned short*)(ws + 29360128);
  unsigned short* wkvbb  = (unsigned short*)(ws + 31981568);
  unsigned short* wob    = (unsigned short*)(ws + 35127296);
  unsigned short* q_a    = (unsigned short*)(ws + 43515904);
  unsigned short* kv_a   = (unsigned short*)(ws + 56098816);
  unsigned short* qfull  = (unsigned short*)(ws + 43515904);
  unsigned short* q_c    = (unsigned short*)(ws + 61341696);
  unsigned short* kv_c   = (unsigned short*)(ws + 73924608);
  unsigned short* krope  = (unsigned short*)(ws + 78118912);
  unsigned short* attno  = (unsigned short*)(ws + 61341696);
  unsigned short* Vattn  = (unsigned short*)(ws + 78643200);   // [B][H][128][2048] (V^T)
  unsigned short* Kattn  = xb;
  unsigned short* kvfull = (unsigned short*)d_out;

  convert_pad<<<8192, 256, 0, stream>>>(x,     xb,    4096, 2048, 4096);
  convert_pad<<<3072, 256, 0, stream>>>(w_qa,  wqab,  1536, 2048, 1536);
  convert_pad<<<3072, 256, 0, stream>>>(w_qb,  wqbb,  2048, 1536, 2048);
  convert_pad<<<1280, 256, 0, stream>>>(w_kva, wkvab,  576, 2048,  640);
  convert_pad<<<1536, 256, 0, stream>>>(w_kvb, wkvbb, 3072,  512, 3072);
  convert_pad<<<4096, 256, 0, stream>>>(w_o,   wob,   2048, 2048, 2048);

  gemm_bt<unsigned short><<<32 * 12, 256, 0, stream>>>(xb, wqab,  q_a,  4096, 1536, 2048);
  gemm_bt<unsigned short><<<32 * 5,  256, 0, stream>>>(xb, wkvab, kv_a, 4096,  640, 2048);

  rms_q<<<4096, 256, 0, stream>>>(q_a, qa_nw, q_c);
  rms_kv<<<4096, 256, 0, stream>>>(kv_a, kva_nw, kv_c, krope);

  gemm_bt<unsigned short><<<32 * 16, 256, 0, stream>>>(q_c,  wqbb,  qfull,  4096, 2048, 1536);
  gemm_bt<unsigned short><<<32 * 24, 256, 0, stream>>>(kv_c, wkvbb, kvfull, 4096, 3072,  512);

  kv_asm_k<<<32768, 256, 0, stream>>>(kvfull, krope, Kattn);
  v_transpose<<<1024, 256, 0, stream>>>(kvfull, Vattn);

  flash_attn<<<512, 256, 0, stream>>>(qfull, Kattn, Vattn, attno);

  gemm_bt<float><<<32 * 16, 256, 0, stream>>>(attno, wob, out, 4096, 2048, 2048);
}

// Round 3
// 310.826 us; speedup vs baseline: 1.3312x; 1.1502x over previous
//
#include <hip/hip_runtime.h>

typedef short bf16x8 __attribute__((ext_vector_type(8)));
typedef unsigned short u16x8 __attribute__((ext_vector_type(8)));
typedef unsigned short u16x4 __attribute__((ext_vector_type(4)));
typedef float f32x4 __attribute__((ext_vector_type(4)));
typedef unsigned u32x4 __attribute__((ext_vector_type(4)));
typedef unsigned u32x2 __attribute__((ext_vector_type(2)));

#define DEV static __device__ __forceinline__

DEV float bf2f(unsigned short u) { return __uint_as_float(((unsigned)u) << 16); }
DEV unsigned short f2bf(float f) {
  unsigned u = __float_as_uint(f);
  return (unsigned short)((u + 0x7fffu + ((u >> 16) & 1u)) >> 16);
}
DEV unsigned cvtpk(float lo, float hi) {
  unsigned r;
  asm("v_cvt_pk_bf16_f32 %0, %1, %2" : "=v"(r) : "v"(lo), "v"(hi));
  return r;
}
DEV void p32swap(unsigned& a, unsigned& b) {
  asm volatile("v_permlane32_swap_b32 %0, %1" : "+v"(a), "+v"(b));
}
DEV void p16swap(unsigned& a, unsigned& b) {
  asm volatile("v_permlane16_swap_b32 %0, %1" : "+v"(a), "+v"(b));
}

#define GLDS16(g, l)                                                                   \
  __builtin_amdgcn_global_load_lds((const __attribute__((address_space(1))) void*)(g), \
                                   (__attribute__((address_space(3))) void*)(l), 16, 0, 0)

// ---------------- fp32 -> bf16 convert with optional zero row-padding ----------------
__global__ __launch_bounds__(256) void convert_pad(const float* __restrict__ src,
                                                   unsigned short* __restrict__ dst,
                                                   int rows, int cols, int dstRows) {
  int i = blockIdx.x * 256 + threadIdx.x;
  int total4 = (dstRows * cols) >> 2;
  if (i >= total4) return;
  int e = i << 2;
  int r = e / cols;
  int c = e - r * cols;
  u16x4 o = {0, 0, 0, 0};
  if (r < rows) {
    const float* p = src + (size_t)r * cols + c;
    o[0] = f2bf(p[0]); o[1] = f2bf(p[1]); o[2] = f2bf(p[2]); o[3] = f2bf(p[3]);
  }
  *(u16x4*)(dst + e) = o;
}

// ---------------- bf16 GEMM: C[M,N] = A[M,K] @ B[N,K]^T  (m97 structure) ----------------
template <typename OutT>
__global__ __launch_bounds__(256, 2) void gemm_bt(const unsigned short* __restrict__ A,
                                                  const unsigned short* __restrict__ B,
                                                  OutT* __restrict__ C, int M, int N, int K) {
  __shared__ __align__(16) unsigned short As[128 * 64];
  __shared__ __align__(16) unsigned short Bs[128 * 64];
  const int tid = threadIdx.x;
  const int lane = tid & 63, wave = tid >> 6;
  const int l16 = lane & 15, lhi = lane >> 4;
  const int nbn = N >> 7;
  const int bm = blockIdx.x / nbn, bn = blockIdx.x - bm * nbn;
  const int m0 = bm << 7, n0 = bn << 7;
  const int wm = (wave >> 1) << 6, wn = (wave & 1) << 6;
  f32x4 acc[4][4] = {};
  for (int k0 = 0; k0 < K; k0 += 64) {
#pragma unroll
    for (int it = 0; it < 4; ++it) {
      int slot = it * 256 + tid;
      int row = slot >> 3, col = (slot & 7) << 3;
      GLDS16(A + (size_t)(m0 + row) * K + k0 + col, As + (it * 256 + wave * 64) * 8);
      GLDS16(B + (size_t)(n0 + row) * K + k0 + col, Bs + (it * 256 + wave * 64) * 8);
    }
    __syncthreads();
#pragma unroll
    for (int ks = 0; ks < 2; ++ks) {
      bf16x8 a[4], b[4];
#pragma unroll
      for (int i = 0; i < 4; ++i) {
        a[i] = *(const bf16x8*)(As + (wm + i * 16 + l16) * 64 + ks * 32 + lhi * 8);
        b[i] = *(const bf16x8*)(Bs + (wn + i * 16 + l16) * 64 + ks * 32 + lhi * 8);
      }
#pragma unroll
      for (int i = 0; i < 4; ++i)
#pragma unroll
        for (int j = 0; j < 4; ++j)
          acc[i][j] = __builtin_amdgcn_mfma_f32_16x16x32_bf16(a[i], b[j], acc[i][j], 0, 0, 0);
    }
    __syncthreads();
  }
#pragma unroll
  for (int i = 0; i < 4; ++i)
#pragma unroll
    for (int j = 0; j < 4; ++j)
#pragma unroll
      for (int r = 0; r < 4; ++r) {
        int row = m0 + wm + i * 16 + lhi * 4 + r;
        int col = n0 + wn + j * 16 + l16;
        float v = acc[i][j][r];
        if constexpr (sizeof(OutT) == 4)
          C[(size_t)row * N + col] = v;
        else
          C[(size_t)row * N + col] = (OutT)f2bf(v);
      }
}

// ---------------- RMS norm over cols 0..1535 of qkva [4096][2176] ----------------
__global__ __launch_bounds__(256) void rms_q(const unsigned short* __restrict__ in,
                                             const float* __restrict__ w,
                                             unsigned short* __restrict__ out) {
  const int row = blockIdx.x, tid = threadIdx.x;
  const unsigned short* p = in + (size_t)row * 2176;
  float f[8];
  float ss = 0.f;
  const bool act = tid < 192;
  if (act) {
    u16x8 v = *(const u16x8*)(p + tid * 8);
#pragma unroll
    for (int j = 0; j < 8; ++j) { f[j] = bf2f(v[j]); ss += f[j] * f[j]; }
  }
#pragma unroll
  for (int m = 1; m <= 32; m <<= 1) ss += __shfl_xor(ss, m);
  __shared__ float red[4];
  if ((tid & 63) == 0) red[tid >> 6] = ss;
  __syncthreads();
  float rstd = rsqrtf((red[0] + red[1] + red[2] + red[3]) * (1.f / 1536.f) + 1e-6f);
  if (act) {
    u16x8 o;
#pragma unroll
    for (int j = 0; j < 8; ++j) o[j] = f2bf(f[j] * rstd * w[tid * 8 + j]);
    *(u16x8*)(out + (size_t)row * 1536 + tid * 8) = o;
  }
}

// ---------------- RMS norm over qkva cols 1536..2047 + RoPE on cols 2048..2111 ----------------
__global__ __launch_bounds__(256) void rms_kv(const unsigned short* __restrict__ qkva,
                                              const float* __restrict__ w,
                                              unsigned short* __restrict__ kvc,
                                              unsigned short* __restrict__ krope) {
  const int row = blockIdx.x, tid = threadIdx.x;
  const unsigned short* p = qkva + (size_t)row * 2176 + 1536;
  float f0 = bf2f(p[tid * 2]), f1 = bf2f(p[tid * 2 + 1]);
  float ss = f0 * f0 + f1 * f1;
#pragma unroll
  for (int m = 1; m <= 32; m <<= 1) ss += __shfl_xor(ss, m);
  __shared__ float red[4];
  if ((tid & 63) == 0) red[tid >> 6] = ss;
  __syncthreads();
  float rstd = rsqrtf((red[0] + red[1] + red[2] + red[3]) * (1.f / 512.f) + 1e-6f);
  kvc[(size_t)row * 512 + tid * 2]     = f2bf(f0 * rstd * w[tid * 2]);
  kvc[(size_t)row * 512 + tid * 2 + 1] = f2bf(f1 * rstd * w[tid * 2 + 1]);
  if (tid < 32) {
    int j = tid;
    float xr = bf2f(p[512 + 2 * j]), xi = bf2f(p[512 + 2 * j + 1]);
    int t = row & 2047;
    float ang = (float)t * powf(10000.f, -(float)j * (1.f / 32.f));
    float c = cosf(ang), s = sinf(ang);
    krope[(size_t)row * 64 + 2 * j]     = f2bf(xr * c - xi * s);
    krope[(size_t)row * 64 + 2 * j + 1] = f2bf(xr * s + xi * c);
  }
}

// ---------------- assemble K in [B][H][T][128] from kv_full + krope ----------------
__global__ __launch_bounds__(256) void kv_asm_k(const unsigned short* __restrict__ kvfull,
                                                const unsigned short* __restrict__ krope,
                                                unsigned short* __restrict__ K) {
  int i = blockIdx.x * 256 + threadIdx.x;
  if (i >= 2 * 2048 * 16 * 128) return;
  int d = i & 127, h = (i >> 7) & 15, tl = i >> 11;
  int b = tl >> 11, t = tl & 2047;
  size_t oidx = ((size_t)((b * 16 + h) * 2048 + t)) * 128 + d;
  K[oidx] = (d < 64) ? kvfull[(size_t)tl * 3072 + h * 192 + d] : krope[(size_t)tl * 64 + d - 64];
}

// ---------------- V^T materialization: VT[b][h][d][t] ----------------
__global__ __launch_bounds__(256) void v_transpose(const unsigned short* __restrict__ kvfull,
                                                   unsigned short* __restrict__ VT) {
  __shared__ unsigned short tile[64][137];
  const int tid = threadIdx.x;
  const int tt = blockIdx.x & 31, h = (blockIdx.x >> 5) & 15, b = blockIdx.x >> 9;
  const int t0 = tt * 64;
#pragma unroll
  for (int it = 0; it < 4; ++it) {
    int s = it * 256 + tid;
    int r = s >> 4, c = (s & 15) << 3;
    u16x8 v = *(const u16x8*)(kvfull + (size_t)(b * 2048 + t0 + r) * 3072 + h * 192 + 64 + c);
    *(u16x8*)(&tile[r][c]) = v;
  }
  __syncthreads();
#pragma unroll
  for (int it = 0; it < 4; ++it) {
    int s = it * 256 + tid;
    int d = s >> 3, tc = (s & 7) << 3;
    u16x8 o;
#pragma unroll
    for (int j = 0; j < 8; ++j) o[j] = tile[tc + j][d];
    *(u16x8*)(VT + ((size_t)(b * 16 + h) * 128 + d) * 2048 + t0 + tc) = o;
  }
}

// ---------------- causal flash attention: swapped-QK^T, in-register softmax ----------------
// Block = (pair pr, h, b); sub-blocks sA=pr, sB=31-pr (64 q-rows each); 4 waves x 16 rows per sub.
// S^T = mfma(K,Q): lane col = q. Softmax lane-local + 2 shfl. P stays in registers
// (cvt_pk_bf16 + permlane16/32 swaps build PV B-fragments). O^T = mfma(VT, P).
// K/V double-buffered in LDS via global_load_lds with XOR-swizzle; 1 barrier/tile.
__global__ __launch_bounds__(256, 2) void flash_attn(const unsigned short* __restrict__ qfull,
                                                     const unsigned short* __restrict__ Kt,  // [B][H][2048][128]
                                                     const unsigned short* __restrict__ Vt,  // [B][H][128][2048]
                                                     unsigned short* __restrict__ out) {
  const int tid = threadIdx.x, lane = tid & 63, wave = tid >> 6;
  const int l16 = lane & 15, lhi = lane >> 4;
  const int pr = blockIdx.x & 15;
  const int h = (blockIdx.x >> 4) & 15;
  const int b = blockIdx.x >> 8;
  const int sA = pr, sB = 31 - pr;
  __shared__ __align__(16) unsigned short Ks[2][64 * 128];
  __shared__ __align__(16) unsigned short Vs[2][64 * 128];

  // --- Q fragments (RoPE on d>=64, fold 1/8 scale); valid as both A- and B-operand ---
  bf16x8 qf[2][4];
  float m_run[2], l_run[2];
  int qrow_g[2];
  f32x4 o_acc[2][8] = {};
#pragma unroll
  for (int u = 0; u < 2; ++u) {
    const int s_u = u ? sB : sA;
    int t = s_u * 64 + wave * 16 + l16;
    qrow_g[u] = t;
    const unsigned short* qrow = qfull + (size_t)(b * 2048 + t) * 2048 + h * 128;
#pragma unroll
    for (int ks = 0; ks < 4; ++ks) {
      u16x8 raw = *(const u16x8*)(qrow + ks * 32 + lhi * 8);
      float f[8];
#pragma unroll
      for (int j = 0; j < 8; ++j) f[j] = bf2f(raw[j]);
      if (ks >= 2) {
#pragma unroll
        for (int pp = 0; pp < 4; ++pp) {
          int d = ks * 32 + lhi * 8 + 2 * pp;
          int jl = (d - 64) >> 1;
          float ang = (float)t * powf(10000.f, -(float)jl * (1.f / 32.f));
          float c = cosf(ang), s = sinf(ang);
          float xr = f[2 * pp], xi = f[2 * pp + 1];
          f[2 * pp] = xr * c - xi * s;
          f[2 * pp + 1] = xr * s + xi * c;
        }
      }
      bf16x8 fr;
#pragma unroll
      for (int j = 0; j < 8; ++j) fr[j] = (short)f2bf(f[j] * 0.125f);
      qf[u][ks] = fr;
    }
    m_run[u] = -1e30f;
    l_run[u] = 0.f;
  }

  const unsigned short* Kbh = Kt + (size_t)(b * 16 + h) * 2048 * 128;
  const unsigned short* Vbh = Vt + (size_t)(b * 16 + h) * 128 * 2048;

  auto stageK = [&](int kt, int buf) {
#pragma unroll
    for (int it = 0; it < 4; ++it) {
      int L = it * 4096 + wave * 1024 + lane * 16;
      int r = L >> 8;
      int w = (L & 255) ^ ((r & 7) << 4);
      GLDS16(Kbh + (size_t)(kt * 64 + r) * 128 + (w >> 1), &Ks[buf][(it * 4096 + wave * 1024) >> 1]);
    }
  };
  auto stageV = [&](int kt, int buf) {
#pragma unroll
    for (int it = 0; it < 4; ++it) {
      int L = it * 4096 + wave * 1024 + lane * 16;
      int d = L >> 7;
      int w = (L & 127) ^ ((d & 7) << 4);
      GLDS16(Vbh + (size_t)d * 2048 + kt * 64 + (w >> 1), &Vs[buf][(it * 4096 + wave * 1024) >> 1]);
    }
  };

  stageK(0, 0);
  stageV(0, 0);
  __syncthreads();
  int cur = 0;

  for (int kt = 0; kt <= sB; ++kt) {
    if (kt < sB) { stageK(kt + 1, cur ^ 1); stageV(kt + 1, cur ^ 1); }  // overlap with compute
    const unsigned short* Kb = Ks[cur];
    const unsigned short* Vb = Vs[cur];
    const bool actA = (kt <= sA);

    // --- S^T = K @ Q^T (lane: col=q=l16, rows k = nt*16 + lhi*4 + r) ---
    f32x4 st[2][4] = {};
    __builtin_amdgcn_s_setprio(1);
#pragma unroll
    for (int ks = 0; ks < 4; ++ks) {
      bf16x8 kf[4];
#pragma unroll
      for (int nt = 0; nt < 4; ++nt) {
        int row = nt * 16 + l16;
        int byteoff = row * 256 + ((ks * 64 + lhi * 16) ^ ((l16 & 7) << 4));
        kf[nt] = *(const bf16x8*)((const char*)Kb + byteoff);
      }
#pragma unroll
      for (int u = 0; u < 2; ++u) {
        if (u == 0 && !actA) continue;
#pragma unroll
        for (int nt = 0; nt < 4; ++nt)
          st[u][nt] = __builtin_amdgcn_mfma_f32_16x16x32_bf16(kf[nt], qf[u][ks], st[u][nt], 0, 0, 0);
      }
    }
    __builtin_amdgcn_s_setprio(0);

    // --- softmax (lane-local rows) + build P fragments in registers ---
    bf16x8 pw[2][2];
#pragma unroll
    for (int u = 0; u < 2; ++u) {
      if (u == 0 && !actA) continue;
      const int s_u = u ? sB : sA;
      if (kt == s_u) {  // diagonal: causal mask
#pragma unroll
        for (int nt = 0; nt < 4; ++nt)
#pragma unroll
          for (int r = 0; r < 4; ++r) {
            int kg = kt * 64 + nt * 16 + lhi * 4 + r;
            st[u][nt][r] = (kg <= qrow_g[u]) ? st[u][nt][r] : -1e30f;
          }
      }
      float mx = -1e30f;
#pragma unroll
      for (int nt = 0; nt < 4; ++nt)
#pragma unroll
        for (int r = 0; r < 4; ++r) mx = fmaxf(mx, st[u][nt][r]);
      mx = fmaxf(mx, __shfl_xor(mx, 16));
      mx = fmaxf(mx, __shfl_xor(mx, 32));
      float mnew = fmaxf(m_run[u], mx);
      float sc = __expf(m_run[u] - mnew);
      m_run[u] = mnew;
      float sum = 0.f;
#pragma unroll
      for (int nt = 0; nt < 4; ++nt)
#pragma unroll
        for (int r = 0; r < 4; ++r) {
          float p = __expf(st[u][nt][r] - mnew);
          st[u][nt][r] = p;
          sum += p;
        }
      sum += __shfl_xor(sum, 16);
      sum += __shfl_xor(sum, 32);
      l_run[u] = l_run[u] * sc + sum;
#pragma unroll
      for (int dt = 0; dt < 8; ++dt) o_acc[u][dt] *= sc;
      // pack P (bf16 pairs), then permlane-route into B-fragment layout
      unsigned pk01[4], pk23[4];
#pragma unroll
      for (int nt = 0; nt < 4; ++nt) {
        pk01[nt] = cvtpk(st[u][nt][0], st[u][nt][1]);
        pk23[nt] = cvtpk(st[u][nt][2], st[u][nt][3]);
      }
#pragma unroll
      for (int k2 = 0; k2 < 2; ++k2) {
        unsigned a0 = pk01[2 * k2], b0 = pk01[2 * k2 + 1];
        unsigned a1 = pk23[2 * k2], b1 = pk23[2 * k2 + 1];
        p32swap(a0, b0); p16swap(a0, b0);  // a0 = words k+{0,1}; b0 = k+{4,5}
        p32swap(a1, b1); p16swap(a1, b1);  // a1 = k+{2,3}; b1 = k+{6,7}
        u32x4 t4 = {a0, a1, b0, b1};
        pw[u][k2] = *(bf16x8*)&t4;
      }
    }

    // --- O^T += V^T @ P (lane: col=q=l16, rows d) ---
    __builtin_amdgcn_s_setprio(1);
#pragma unroll
    for (int k2 = 0; k2 < 2; ++k2)
#pragma unroll
      for (int dt = 0; dt < 8; ++dt) {
        int row = dt * 16 + l16;
        int byteoff = row * 128 + ((k2 * 64 + lhi * 16) ^ ((l16 & 7) << 4));
        bf16x8 vf = *(const bf16x8*)((const char*)Vb + byteoff);
#pragma unroll
        for (int u = 0; u < 2; ++u) {
          if (u == 0 && !actA) continue;
          o_acc[u][dt] = __builtin_amdgcn_mfma_f32_16x16x32_bf16(vf, pw[u][k2], o_acc[u][dt], 0, 0, 0);
        }
      }
    __builtin_amdgcn_s_setprio(0);

    __syncthreads();  // staged tile landed; all reads of cur done
    cur ^= 1;
  }

  // --- epilogue: lane holds O^T[d = dt*16+lhi*4+r][q=l16]; packed 8B stores ---
#pragma unroll
  for (int u = 0; u < 2; ++u) {
    float inv = 1.0f / l_run[u];
    unsigned short* orow = out + (size_t)(b * 2048 + qrow_g[u]) * 2048 + h * 128;
#pragma unroll
    for (int dt = 0; dt < 8; ++dt) {
      unsigned w01 = cvtpk(o_acc[u][dt][0] * inv, o_acc[u][dt][1] * inv);
      unsigned w23 = cvtpk(o_acc[u][dt][2] * inv, o_acc[u][dt][3] * inv);
      u32x2 st2 = {w01, w23};
      *(u32x2*)(orow + dt * 16 + lhi * 4) = st2;
    }
  }
}

// =====================================================================================
extern "C" void kernel_launch(void* const* d_in, const int* in_sizes, int n_in,
                              void* d_out, int out_size, void* d_ws, size_t ws_size,
                              hipStream_t stream) {
  (void)in_sizes; (void)n_in; (void)out_size; (void)ws_size;
  const float* x      = (const float*)d_in[0];
  const float* w_qa   = (const float*)d_in[2];
  const float* qa_nw  = (const float*)d_in[3];
  const float* w_qb   = (const float*)d_in[4];
  const float* w_kva  = (const float*)d_in[5];
  const float* kva_nw = (const float*)d_in[6];
  const float* w_kvb  = (const float*)d_in[7];
  const float* w_o    = (const float*)d_in[8];
  float* out = (float*)d_out;
  char* ws = (char*)d_ws;

  unsigned short* xb     = (unsigned short*)(ws + 0);          // dead after fused GEMM -> Kattn
  unsigned short* wqkva  = (unsigned short*)(ws + 16777216);   // [2176][2048] (w_qa ++ w_kva pad)
  unsigned short* wqbb   = (unsigned short*)(ws + 25690112);
  unsigned short* wkvbb  = (unsigned short*)(ws + 31981568);
  unsigned short* wob    = (unsigned short*)(ws + 35127296);
  unsigned short* qkva   = (unsigned short*)(ws + 43515904);   // [4096][2176]
  unsigned short* qfull  = (unsigned short*)(ws + 43515904);   // alias (qkva dead after rms)
  unsigned short* q_c    = (unsigned short*)(ws + 61341696);   // [4096][1536]
  unsigned short* kv_c   = (unsigned short*)(ws + 73924608);   // [4096][512]
  unsigned short* krope  = (unsigned short*)(ws + 78118912);   // [4096][64]
  unsigned short* attno  = (unsigned short*)(ws + 61341696);   // alias (q_c+kv_c dead)
  unsigned short* Vattn  = (unsigned short*)(ws + 78643200);   // [B][H][128][2048] (V^T)
  unsigned short* Kattn  = xb;
  unsigned short* kvfull = (unsigned short*)d_out;             // scratch in d_out

  convert_pad<<<8192, 256, 0, stream>>>(x,     xb,    4096, 2048, 4096);
  convert_pad<<<3072, 256, 0, stream>>>(w_qa,  wqkva, 1536, 2048, 1536);
  convert_pad<<<1280, 256, 0, stream>>>(w_kva, wqkva + (size_t)1536 * 2048, 576, 2048, 640);
  convert_pad<<<3072, 256, 0, stream>>>(w_qb,  wqbb,  2048, 1536, 2048);
  convert_pad<<<1536, 256, 0, stream>>>(w_kvb, wkvbb, 3072,  512, 3072);
  convert_pad<<<4096, 256, 0, stream>>>(w_o,   wob,   2048, 2048, 2048);

  // fused low-rank projections: [4096][2176] = xb @ [w_qa ++ w_kva]^T
  gemm_bt<unsigned short><<<32 * 17, 256, 0, stream>>>(xb, wqkva, qkva, 4096, 2176, 2048);

  rms_q<<<4096, 256, 0, stream>>>(qkva, qa_nw, q_c);
  rms_kv<<<4096, 256, 0, stream>>>(qkva, kva_nw, kv_c, krope);

  gemm_bt<unsigned short><<<32 * 16, 256, 0, stream>>>(q_c,  wqbb,  qfull,  4096, 2048, 1536);
  gemm_bt<unsigned short><<<32 * 24, 256, 0, stream>>>(kv_c, wkvbb, kvfull, 4096, 3072,  512);

  kv_asm_k<<<32768, 256, 0, stream>>>(kvfull, krope, Kattn);
  v_transpose<<<1024, 256, 0, stream>>>(kvfull, Vattn);

  flash_attn<<<512, 256, 0, stream>>>(qfull, Kattn, Vattn, attno);

  gemm_bt<float><<<32 * 16, 256, 0, stream>>>(attno, wob, out, 4096, 2048, 2048);
}

// Round 4
// 286.626 us; speedup vs baseline: 1.4436x; 1.0844x over previous
//
#include <hip/hip_runtime.h>

typedef short bf16x8 __attribute__((ext_vector_type(8)));
typedef unsigned short u16x8 __attribute__((ext_vector_type(8)));
typedef unsigned short u16x4 __attribute__((ext_vector_type(4)));
typedef float f32x4 __attribute__((ext_vector_type(4)));
typedef unsigned u32x4 __attribute__((ext_vector_type(4)));
typedef unsigned u32x2 __attribute__((ext_vector_type(2)));

#define DEV static __device__ __forceinline__

DEV float bf2f(unsigned short u) { return __uint_as_float(((unsigned)u) << 16); }
DEV unsigned short f2bf(float f) {
  unsigned u = __float_as_uint(f);
  return (unsigned short)((u + 0x7fffu + ((u >> 16) & 1u)) >> 16);
}
DEV unsigned cvtpk(float lo, float hi) {
  unsigned r;
  asm("v_cvt_pk_bf16_f32 %0, %1, %2" : "=v"(r) : "v"(lo), "v"(hi));
  return r;
}
DEV void p32swap(unsigned& a, unsigned& b) {
  asm volatile("v_permlane32_swap_b32 %0, %1" : "+v"(a), "+v"(b));
}
DEV void p16swap(unsigned& a, unsigned& b) {
  asm volatile("v_permlane16_swap_b32 %0, %1" : "+v"(a), "+v"(b));
}

#define GLDS16(g, l)                                                                   \
  __builtin_amdgcn_global_load_lds((const __attribute__((address_space(1))) void*)(g), \
                                   (__attribute__((address_space(3))) void*)(l), 16, 0, 0)

// ---------------- fused fp32 -> bf16 converts (all 6 tensors, one launch) ----------------
DEV void cvt_body(const float* __restrict__ src, unsigned short* __restrict__ dst,
                  int rows, int cols, int dstRows, int bid) {
  int i = bid * 256 + (int)threadIdx.x;
  int e = i << 2;
  int r = e / cols;            // cols is compile-time const per call site -> magic mul
  int c = e - r * cols;
  u16x4 o = {0, 0, 0, 0};
  if (r < rows) {
    const float* p = src + (size_t)r * cols + c;
    o[0] = f2bf(p[0]); o[1] = f2bf(p[1]); o[2] = f2bf(p[2]); o[3] = f2bf(p[3]);
  }
  *(u16x4*)(dst + e) = o;
}

__global__ __launch_bounds__(256) void convert_all(
    const float* __restrict__ x, const float* __restrict__ w_qa, const float* __restrict__ w_kva,
    const float* __restrict__ w_qb, const float* __restrict__ w_kvb, const float* __restrict__ w_o,
    unsigned short* __restrict__ xb, unsigned short* __restrict__ wqkva,
    unsigned short* __restrict__ wqbb, unsigned short* __restrict__ wkvbb,
    unsigned short* __restrict__ wob) {
  int bid = blockIdx.x;
  if (bid < 8192)        cvt_body(x,     xb,                        4096, 2048, 4096, bid);
  else if (bid < 11264)  cvt_body(w_qa,  wqkva,                     1536, 2048, 1536, bid - 8192);
  else if (bid < 12544)  cvt_body(w_kva, wqkva + (size_t)1536*2048,  576, 2048,  640, bid - 11264);
  else if (bid < 15616)  cvt_body(w_qb,  wqbb,                      2048, 1536, 2048, bid - 12544);
  else if (bid < 17152)  cvt_body(w_kvb, wkvbb,                     3072,  512, 3072, bid - 15616);
  else                   cvt_body(w_o,   wob,                       2048, 2048, 2048, bid - 17152);
}

// ---------------- bf16 GEMM: C[M,N] = A[M,K] @ B[N,K]^T  (m97 structure) ----------------
template <typename OutT>
__global__ __launch_bounds__(256, 2) void gemm_bt(const unsigned short* __restrict__ A,
                                                  const unsigned short* __restrict__ B,
                                                  OutT* __restrict__ C, int M, int N, int K) {
  __shared__ __align__(16) unsigned short As[128 * 64];
  __shared__ __align__(16) unsigned short Bs[128 * 64];
  const int tid = threadIdx.x;
  const int lane = tid & 63, wave = tid >> 6;
  const int l16 = lane & 15, lhi = lane >> 4;
  const int nbn = N >> 7;
  const int bm = blockIdx.x / nbn, bn = blockIdx.x - bm * nbn;
  const int m0 = bm << 7, n0 = bn << 7;
  const int wm = (wave >> 1) << 6, wn = (wave & 1) << 6;
  f32x4 acc[4][4] = {};
  for (int k0 = 0; k0 < K; k0 += 64) {
#pragma unroll
    for (int it = 0; it < 4; ++it) {
      int slot = it * 256 + tid;
      int row = slot >> 3, col = (slot & 7) << 3;
      GLDS16(A + (size_t)(m0 + row) * K + k0 + col, As + (it * 256 + wave * 64) * 8);
      GLDS16(B + (size_t)(n0 + row) * K + k0 + col, Bs + (it * 256 + wave * 64) * 8);
    }
    __syncthreads();
#pragma unroll
    for (int ks = 0; ks < 2; ++ks) {
      bf16x8 a[4], b[4];
#pragma unroll
      for (int i = 0; i < 4; ++i) {
        a[i] = *(const bf16x8*)(As + (wm + i * 16 + l16) * 64 + ks * 32 + lhi * 8);
        b[i] = *(const bf16x8*)(Bs + (wn + i * 16 + l16) * 64 + ks * 32 + lhi * 8);
      }
#pragma unroll
      for (int i = 0; i < 4; ++i)
#pragma unroll
        for (int j = 0; j < 4; ++j)
          acc[i][j] = __builtin_amdgcn_mfma_f32_16x16x32_bf16(a[i], b[j], acc[i][j], 0, 0, 0);
    }
    __syncthreads();
  }
#pragma unroll
  for (int i = 0; i < 4; ++i)
#pragma unroll
    for (int j = 0; j < 4; ++j)
#pragma unroll
      for (int r = 0; r < 4; ++r) {
        int row = m0 + wm + i * 16 + lhi * 4 + r;
        int col = n0 + wn + j * 16 + l16;
        float v = acc[i][j][r];
        if constexpr (sizeof(OutT) == 4)
          C[(size_t)row * N + col] = v;
        else
          C[(size_t)row * N + col] = (OutT)f2bf(v);
      }
}

// ---------------- fused RMS norms: q (1536) + kv (512) + RoPE of shared k_rope ----------------
__global__ __launch_bounds__(256) void rms_fused(const unsigned short* __restrict__ qkva,
                                                 const float* __restrict__ qw,
                                                 const float* __restrict__ kvw,
                                                 unsigned short* __restrict__ q_c,
                                                 unsigned short* __restrict__ kv_c,
                                                 unsigned short* __restrict__ krope) {
  const int row = blockIdx.x, tid = threadIdx.x;
  const unsigned short* p = qkva + (size_t)row * 2176;
  float fq[8];
  float ssq = 0.f;
  const bool act = tid < 192;
  if (act) {
    u16x8 v = *(const u16x8*)(p + tid * 8);
#pragma unroll
    for (int j = 0; j < 8; ++j) { fq[j] = bf2f(v[j]); ssq += fq[j] * fq[j]; }
  }
  float f0 = bf2f(p[1536 + tid * 2]), f1 = bf2f(p[1536 + tid * 2 + 1]);
  float sskv = f0 * f0 + f1 * f1;
#pragma unroll
  for (int m = 1; m <= 32; m <<= 1) {
    ssq += __shfl_xor(ssq, m);
    sskv += __shfl_xor(sskv, m);
  }
  __shared__ float rq[4], rkv[4];
  if ((tid & 63) == 0) { rq[tid >> 6] = ssq; rkv[tid >> 6] = sskv; }
  __syncthreads();
  float rstdq = rsqrtf((rq[0] + rq[1] + rq[2] + rq[3]) * (1.f / 1536.f) + 1e-6f);
  float rstdkv = rsqrtf((rkv[0] + rkv[1] + rkv[2] + rkv[3]) * (1.f / 512.f) + 1e-6f);
  if (act) {
    u16x8 o;
#pragma unroll
    for (int j = 0; j < 8; ++j) o[j] = f2bf(fq[j] * rstdq * qw[tid * 8 + j]);
    *(u16x8*)(q_c + (size_t)row * 1536 + tid * 8) = o;
  }
  kv_c[(size_t)row * 512 + tid * 2]     = f2bf(f0 * rstdkv * kvw[tid * 2]);
  kv_c[(size_t)row * 512 + tid * 2 + 1] = f2bf(f1 * rstdkv * kvw[tid * 2 + 1]);
  if (tid < 32) {
    int j = tid;
    float xr = bf2f(p[2048 + 2 * j]), xi = bf2f(p[2048 + 2 * j + 1]);
    int t = row & 2047;
    float ang = (float)t * powf(10000.f, -(float)j * (1.f / 32.f));
    float c = cosf(ang), s = sinf(ang);
    krope[(size_t)row * 64 + 2 * j]     = f2bf(xr * c - xi * s);
    krope[(size_t)row * 64 + 2 * j + 1] = f2bf(xr * s + xi * c);
  }
}

// ---------------- V^T materialization: VT[b][h][d][t] ----------------
__global__ __launch_bounds__(256) void v_transpose(const unsigned short* __restrict__ kvfull,
                                                   unsigned short* __restrict__ VT) {
  __shared__ unsigned short tile[64][137];
  const int tid = threadIdx.x;
  const int tt = blockIdx.x & 31, h = (blockIdx.x >> 5) & 15, b = blockIdx.x >> 9;
  const int t0 = tt * 64;
#pragma unroll
  for (int it = 0; it < 4; ++it) {
    int s = it * 256 + tid;
    int r = s >> 4, c = (s & 15) << 3;
    u16x8 v = *(const u16x8*)(kvfull + (size_t)(b * 2048 + t0 + r) * 3072 + h * 192 + 64 + c);
    *(u16x8*)(&tile[r][c]) = v;
  }
  __syncthreads();
#pragma unroll
  for (int it = 0; it < 4; ++it) {
    int s = it * 256 + tid;
    int d = s >> 3, tc = (s & 7) << 3;
    u16x8 o;
#pragma unroll
    for (int j = 0; j < 8; ++j) o[j] = tile[tc + j][d];
    *(u16x8*)(VT + ((size_t)(b * 16 + h) * 128 + d) * 2048 + t0 + tc) = o;
  }
}

// ---------------- causal flash attention ----------------
// Swapped-QK^T (S^T lane col = q), in-register softmax in exp2 domain, defer-max,
// P kept in registers (cvt_pk + permlane), O^T = mfma(V^T, P).
// K staged DIRECTLY from kvfull (content) + krope (rope, shared across heads).
// XCD swizzle: all 16 pr-blocks of one (b,h) on one XCD for K/V L2 reuse.
__global__ __launch_bounds__(256, 2) void flash_attn(const unsigned short* __restrict__ qfull,
                                                     const unsigned short* __restrict__ kvfull, // [4096][3072]
                                                     const unsigned short* __restrict__ krope,  // [4096][64]
                                                     const unsigned short* __restrict__ Vt,     // [B][H][128][2048]
                                                     unsigned short* __restrict__ out) {
  const int tid = threadIdx.x, lane = tid & 63, wave = tid >> 6;
  const int l16 = lane & 15, lhi = lane >> 4;
  const int bid = blockIdx.x;
  const int vid = (bid & 7) * 64 + (bid >> 3);  // XCD-chunk swizzle (bijective on 512)
  const int pr = vid & 15;
  const int h = (vid >> 4) & 15;
  const int b = vid >> 8;
  const int sA = pr, sB = 31 - pr;
  __shared__ __align__(16) unsigned short Ks[2][64 * 128];
  __shared__ __align__(16) unsigned short Vs[2][64 * 128];

  // --- Q fragments: RoPE on d>=64; fold (1/8)*log2(e) so softmax uses exp2 directly ---
  const float QSCALE = 0.125f * 1.44269504089f;
  bf16x8 qf[2][4];
  float m_run[2], l_run[2];
  int qrow_g[2];
  f32x4 o_acc[2][8] = {};
#pragma unroll
  for (int u = 0; u < 2; ++u) {
    const int s_u = u ? sB : sA;
    int t = s_u * 64 + wave * 16 + l16;
    qrow_g[u] = t;
    const unsigned short* qrow = qfull + (size_t)(b * 2048 + t) * 2048 + h * 128;
#pragma unroll
    for (int ks = 0; ks < 4; ++ks) {
      u16x8 raw = *(const u16x8*)(qrow + ks * 32 + lhi * 8);
      float f[8];
#pragma unroll
      for (int j = 0; j < 8; ++j) f[j] = bf2f(raw[j]);
      if (ks >= 2) {
#pragma unroll
        for (int pp = 0; pp < 4; ++pp) {
          int d = ks * 32 + lhi * 8 + 2 * pp;
          int jl = (d - 64) >> 1;
          float ang = (float)t * powf(10000.f, -(float)jl * (1.f / 32.f));
          float c = cosf(ang), s = sinf(ang);
          float xr = f[2 * pp], xi = f[2 * pp + 1];
          f[2 * pp] = xr * c - xi * s;
          f[2 * pp + 1] = xr * s + xi * c;
        }
      }
      bf16x8 fr;
#pragma unroll
      for (int j = 0; j < 8; ++j) fr[j] = (short)f2bf(f[j] * QSCALE);
      qf[u][ks] = fr;
    }
    m_run[u] = -1e30f;
    l_run[u] = 0.f;
  }

  const int bT = b * 2048;
  const unsigned short* Vbh = Vt + (size_t)(b * 16 + h) * 128 * 2048;

  // K content from kvfull, K rope from krope (per-lane source select; LDS dest linear)
  auto stageK = [&](int kt, int buf) {
#pragma unroll
    for (int it = 0; it < 4; ++it) {
      int L = it * 4096 + wave * 1024 + lane * 16;
      int r = L >> 8;
      int w = (L & 255) ^ ((r & 7) << 4);
      int c = w >> 1;  // elem col, multiple of 8, 0..127
      int tl = bT + kt * 64 + r;
      const unsigned short* src = (c < 64) ? kvfull + (size_t)tl * 3072 + h * 192 + c
                                           : krope + (size_t)tl * 64 + (c - 64);
      GLDS16(src, &Ks[buf][(it * 4096 + wave * 1024) >> 1]);
    }
  };
  auto stageV = [&](int kt, int buf) {
#pragma unroll
    for (int it = 0; it < 4; ++it) {
      int L = it * 4096 + wave * 1024 + lane * 16;
      int d = L >> 7;
      int w = (L & 127) ^ ((d & 7) << 4);
      GLDS16(Vbh + (size_t)d * 2048 + kt * 64 + (w >> 1), &Vs[buf][(it * 4096 + wave * 1024) >> 1]);
    }
  };

  stageK(0, 0);
  stageV(0, 0);
  __syncthreads();
  int cur = 0;

  for (int kt = 0; kt <= sB; ++kt) {
    if (kt < sB) { stageK(kt + 1, cur ^ 1); stageV(kt + 1, cur ^ 1); }
    const unsigned short* Kb = Ks[cur];
    const unsigned short* Vb = Vs[cur];
    const bool actA = (kt <= sA);

    // --- S^T = K @ Q^T ---
    f32x4 st[2][4] = {};
    __builtin_amdgcn_s_setprio(1);
#pragma unroll
    for (int ks = 0; ks < 4; ++ks) {
      bf16x8 kf[4];
#pragma unroll
      for (int nt = 0; nt < 4; ++nt) {
        int row = nt * 16 + l16;
        int byteoff = row * 256 + ((ks * 64 + lhi * 16) ^ ((l16 & 7) << 4));
        kf[nt] = *(const bf16x8*)((const char*)Kb + byteoff);
      }
#pragma unroll
      for (int u = 0; u < 2; ++u) {
        if (u == 0 && !actA) continue;
#pragma unroll
        for (int nt = 0; nt < 4; ++nt)
          st[u][nt] = __builtin_amdgcn_mfma_f32_16x16x32_bf16(kf[nt], qf[u][ks], st[u][nt], 0, 0, 0);
      }
    }
    __builtin_amdgcn_s_setprio(0);

    // --- softmax (exp2 domain, defer-max) + P fragments in registers ---
    bf16x8 pw[2][2];
#pragma unroll
    for (int u = 0; u < 2; ++u) {
      if (u == 0 && !actA) continue;
      const int s_u = u ? sB : sA;
      if (kt == s_u) {  // diagonal: causal mask
#pragma unroll
        for (int nt = 0; nt < 4; ++nt)
#pragma unroll
          for (int r = 0; r < 4; ++r) {
            int kg = kt * 64 + nt * 16 + lhi * 4 + r;
            st[u][nt][r] = (kg <= qrow_g[u]) ? st[u][nt][r] : -1e30f;
          }
      }
      float mx = -1e30f;
#pragma unroll
      for (int nt = 0; nt < 4; ++nt)
#pragma unroll
        for (int r = 0; r < 4; ++r) mx = fmaxf(mx, st[u][nt][r]);
      mx = fmaxf(mx, __shfl_xor(mx, 16));
      mx = fmaxf(mx, __shfl_xor(mx, 32));
      if (__ballot(mx > m_run[u] + 8.f)) {  // T13: rescale only on real max growth
        float mnew = fmaxf(m_run[u], mx);
        float sc = exp2f(m_run[u] - mnew);
        m_run[u] = mnew;
        l_run[u] *= sc;
#pragma unroll
        for (int dt = 0; dt < 8; ++dt) o_acc[u][dt] *= sc;
      }
      const float mcur = m_run[u];
      float sum = 0.f;
#pragma unroll
      for (int nt = 0; nt < 4; ++nt)
#pragma unroll
        for (int r = 0; r < 4; ++r) {
          float p = exp2f(st[u][nt][r] - mcur);
          st[u][nt][r] = p;
          sum += p;
        }
      sum += __shfl_xor(sum, 16);
      sum += __shfl_xor(sum, 32);
      l_run[u] += sum;
      unsigned pk01[4], pk23[4];
#pragma unroll
      for (int nt = 0; nt < 4; ++nt) {
        pk01[nt] = cvtpk(st[u][nt][0], st[u][nt][1]);
        pk23[nt] = cvtpk(st[u][nt][2], st[u][nt][3]);
      }
#pragma unroll
      for (int k2 = 0; k2 < 2; ++k2) {
        unsigned a0 = pk01[2 * k2], b0 = pk01[2 * k2 + 1];
        unsigned a1 = pk23[2 * k2], b1 = pk23[2 * k2 + 1];
        p32swap(a0, b0); p16swap(a0, b0);
        p32swap(a1, b1); p16swap(a1, b1);
        u32x4 t4 = {a0, a1, b0, b1};
        pw[u][k2] = *(bf16x8*)&t4;
      }
    }

    // --- O^T += V^T @ P ---
    __builtin_amdgcn_s_setprio(1);
#pragma unroll
    for (int k2 = 0; k2 < 2; ++k2)
#pragma unroll
      for (int dt = 0; dt < 8; ++dt) {
        int row = dt * 16 + l16;
        int byteoff = row * 128 + ((k2 * 64 + lhi * 16) ^ ((l16 & 7) << 4));
        bf16x8 vf = *(const bf16x8*)((const char*)Vb + byteoff);
#pragma unroll
        for (int u = 0; u < 2; ++u) {
          if (u == 0 && !actA) continue;
          o_acc[u][dt] = __builtin_amdgcn_mfma_f32_16x16x32_bf16(vf, pw[u][k2], o_acc[u][dt], 0, 0, 0);
        }
      }
    __builtin_amdgcn_s_setprio(0);

    __syncthreads();
    cur ^= 1;
  }

  // --- epilogue ---
#pragma unroll
  for (int u = 0; u < 2; ++u) {
    float inv = 1.0f / l_run[u];
    unsigned short* orow = out + (size_t)(b * 2048 + qrow_g[u]) * 2048 + h * 128;
#pragma unroll
    for (int dt = 0; dt < 8; ++dt) {
      unsigned w01 = cvtpk(o_acc[u][dt][0] * inv, o_acc[u][dt][1] * inv);
      unsigned w23 = cvtpk(o_acc[u][dt][2] * inv, o_acc[u][dt][3] * inv);
      u32x2 st2 = {w01, w23};
      *(u32x2*)(orow + dt * 16 + lhi * 4) = st2;
    }
  }
}

// =====================================================================================
extern "C" void kernel_launch(void* const* d_in, const int* in_sizes, int n_in,
                              void* d_out, int out_size, void* d_ws, size_t ws_size,
                              hipStream_t stream) {
  (void)in_sizes; (void)n_in; (void)out_size; (void)ws_size;
  const float* x      = (const float*)d_in[0];
  const float* w_qa   = (const float*)d_in[2];
  const float* qa_nw  = (const float*)d_in[3];
  const float* w_qb   = (const float*)d_in[4];
  const float* w_kva  = (const float*)d_in[5];
  const float* kva_nw = (const float*)d_in[6];
  const float* w_kvb  = (const float*)d_in[7];
  const float* w_o    = (const float*)d_in[8];
  float* out = (float*)d_out;
  char* ws = (char*)d_ws;

  unsigned short* xb     = (unsigned short*)(ws + 0);
  unsigned short* wqkva  = (unsigned short*)(ws + 16777216);   // [2176][2048]
  unsigned short* wqbb   = (unsigned short*)(ws + 25690112);
  unsigned short* wkvbb  = (unsigned short*)(ws + 31981568);
  unsigned short* wob    = (unsigned short*)(ws + 35127296);
  unsigned short* qkva   = (unsigned short*)(ws + 43515904);   // [4096][2176]
  unsigned short* qfull  = (unsigned short*)(ws + 43515904);   // alias (qkva dead after rms)
  unsigned short* q_c    = (unsigned short*)(ws + 61341696);   // [4096][1536]
  unsigned short* kv_c   = (unsigned short*)(ws + 73924608);   // [4096][512]
  unsigned short* krope  = (unsigned short*)(ws + 78118912);   // [4096][64]
  unsigned short* attno  = (unsigned short*)(ws + 61341696);   // alias (q_c+kv_c dead)
  unsigned short* Vattn  = (unsigned short*)(ws + 78643200);   // [B][H][128][2048]
  unsigned short* kvfull = (unsigned short*)d_out;             // scratch in d_out

  convert_all<<<21248, 256, 0, stream>>>(x, w_qa, w_kva, w_qb, w_kvb, w_o,
                                         xb, wqkva, wqbb, wkvbb, wob);

  // fused low-rank projections: [4096][2176] = xb @ [w_qa ++ w_kva]^T
  gemm_bt<unsigned short><<<32 * 17, 256, 0, stream>>>(xb, wqkva, qkva, 4096, 2176, 2048);

  rms_fused<<<4096, 256, 0, stream>>>(qkva, qa_nw, kva_nw, q_c, kv_c, krope);

  gemm_bt<unsigned short><<<32 * 16, 256, 0, stream>>>(q_c,  wqbb,  qfull,  4096, 2048, 1536);
  gemm_bt<unsigned short><<<32 * 24, 256, 0, stream>>>(kv_c, wkvbb, kvfull, 4096, 3072,  512);

  v_transpose<<<1024, 256, 0, stream>>>(kvfull, Vattn);

  flash_attn<<<512, 256, 0, stream>>>(qfull, kvfull, krope, Vattn, attno);

  gemm_bt<float><<<32 * 16, 256, 0, stream>>>(attno, wob, out, 4096, 2048, 2048);
}

// Round 5
// 282.039 us; speedup vs baseline: 1.4670x; 1.0163x over previous
//
#include <hip/hip_runtime.h>

typedef short bf16x8 __attribute__((ext_vector_type(8)));
typedef unsigned short u16x8 __attribute__((ext_vector_type(8)));
typedef unsigned short u16x4 __attribute__((ext_vector_type(4)));
typedef float f32x4 __attribute__((ext_vector_type(4)));
typedef unsigned u32x4 __attribute__((ext_vector_type(4)));
typedef unsigned u32x2 __attribute__((ext_vector_type(2)));

#define DEV static __device__ __forceinline__

DEV float bf2f(unsigned short u) { return __uint_as_float(((unsigned)u) << 16); }
DEV unsigned short f2bf(float f) {
  unsigned u = __float_as_uint(f);
  return (unsigned short)((u + 0x7fffu + ((u >> 16) & 1u)) >> 16);
}
DEV unsigned cvtpk(float lo, float hi) {
  unsigned r;
  asm("v_cvt_pk_bf16_f32 %0, %1, %2" : "=v"(r) : "v"(lo), "v"(hi));
  return r;
}
DEV void p32swap(unsigned& a, unsigned& b) {
  asm volatile("v_permlane32_swap_b32 %0, %1" : "+v"(a), "+v"(b));
}
DEV void p16swap(unsigned& a, unsigned& b) {
  asm volatile("v_permlane16_swap_b32 %0, %1" : "+v"(a), "+v"(b));
}

#define GLDS16(g, l)                                                                   \
  __builtin_amdgcn_global_load_lds((const __attribute__((address_space(1))) void*)(g), \
                                   (__attribute__((address_space(3))) void*)(l), 16, 0, 0)

// ---------------- fused fp32 -> bf16 converts (all 6 tensors, one launch) ----------------
DEV void cvt_body(const float* __restrict__ src, unsigned short* __restrict__ dst,
                  int rows, int cols, int dstRows, int bid) {
  int i = bid * 256 + (int)threadIdx.x;
  int e = i << 2;
  int r = e / cols;
  int c = e - r * cols;
  u16x4 o = {0, 0, 0, 0};
  if (r < rows) {
    const float* p = src + (size_t)r * cols + c;
    o[0] = f2bf(p[0]); o[1] = f2bf(p[1]); o[2] = f2bf(p[2]); o[3] = f2bf(p[3]);
  }
  *(u16x4*)(dst + e) = o;
}

__global__ __launch_bounds__(256) void convert_all(
    const float* __restrict__ x, const float* __restrict__ w_qa, const float* __restrict__ w_kva,
    const float* __restrict__ w_qb, const float* __restrict__ w_kvb, const float* __restrict__ w_o,
    unsigned short* __restrict__ xb, unsigned short* __restrict__ wqkva,
    unsigned short* __restrict__ wqbb, unsigned short* __restrict__ wkvbb,
    unsigned short* __restrict__ wob) {
  int bid = blockIdx.x;
  if (bid < 8192)        cvt_body(x,     xb,                        4096, 2048, 4096, bid);
  else if (bid < 11264)  cvt_body(w_qa,  wqkva,                     1536, 2048, 1536, bid - 8192);
  else if (bid < 12544)  cvt_body(w_kva, wqkva + (size_t)1536*2048,  576, 2048,  640, bid - 11264);
  else if (bid < 15616)  cvt_body(w_qb,  wqbb,                      2048, 1536, 2048, bid - 12544);
  else if (bid < 17152)  cvt_body(w_kvb, wkvbb,                     3072,  512, 3072, bid - 15616);
  else                   cvt_body(w_o,   wob,                       2048, 2048, 2048, bid - 17152);
}

// ---------------- bf16 GEMM: C[M,N] = A[M,K] @ B[N,K]^T  (m97 structure) ----------------
template <typename OutT>
__global__ __launch_bounds__(256, 2) void gemm_bt(const unsigned short* __restrict__ A,
                                                  const unsigned short* __restrict__ B,
                                                  OutT* __restrict__ C, int M, int N, int K) {
  __shared__ __align__(16) unsigned short As[128 * 64];
  __shared__ __align__(16) unsigned short Bs[128 * 64];
  const int tid = threadIdx.x;
  const int lane = tid & 63, wave = tid >> 6;
  const int l16 = lane & 15, lhi = lane >> 4;
  const int nbn = N >> 7;
  const int bm = blockIdx.x / nbn, bn = blockIdx.x - bm * nbn;
  const int m0 = bm << 7, n0 = bn << 7;
  const int wm = (wave >> 1) << 6, wn = (wave & 1) << 6;
  f32x4 acc[4][4] = {};
  for (int k0 = 0; k0 < K; k0 += 64) {
#pragma unroll
    for (int it = 0; it < 4; ++it) {
      int slot = it * 256 + tid;
      int row = slot >> 3, col = (slot & 7) << 3;
      GLDS16(A + (size_t)(m0 + row) * K + k0 + col, As + (it * 256 + wave * 64) * 8);
      GLDS16(B + (size_t)(n0 + row) * K + k0 + col, Bs + (it * 256 + wave * 64) * 8);
    }
    __syncthreads();
#pragma unroll
    for (int ks = 0; ks < 2; ++ks) {
      bf16x8 a[4], b[4];
#pragma unroll
      for (int i = 0; i < 4; ++i) {
        a[i] = *(const bf16x8*)(As + (wm + i * 16 + l16) * 64 + ks * 32 + lhi * 8);
        b[i] = *(const bf16x8*)(Bs + (wn + i * 16 + l16) * 64 + ks * 32 + lhi * 8);
      }
#pragma unroll
      for (int i = 0; i < 4; ++i)
#pragma unroll
        for (int j = 0; j < 4; ++j)
          acc[i][j] = __builtin_amdgcn_mfma_f32_16x16x32_bf16(a[i], b[j], acc[i][j], 0, 0, 0);
    }
    __syncthreads();
  }
#pragma unroll
  for (int i = 0; i < 4; ++i)
#pragma unroll
    for (int j = 0; j < 4; ++j)
#pragma unroll
      for (int r = 0; r < 4; ++r) {
        int row = m0 + wm + i * 16 + lhi * 4 + r;
        int col = n0 + wn + j * 16 + l16;
        float v = acc[i][j][r];
        if constexpr (sizeof(OutT) == 4)
          C[(size_t)row * N + col] = v;
        else
          C[(size_t)row * N + col] = (OutT)f2bf(v);
      }
}

// ---------------- kvb GEMM: writes K-content cols to kvfull, V cols transposed to VT ----------------
__global__ __launch_bounds__(256, 2) void gemm_kvb(const unsigned short* __restrict__ A,  // kv_c [4096][512]
                                                   const unsigned short* __restrict__ B,  // wkvbb [3072][512]
                                                   unsigned short* __restrict__ kvfull,   // [4096][3072] (k cols only)
                                                   unsigned short* __restrict__ VT) {     // [B][16][128][2048]
  const int M = 4096, N = 3072, K = 512;
  __shared__ __align__(16) unsigned short As[128 * 64];
  __shared__ __align__(16) unsigned short Bs[128 * 64];
  const int tid = threadIdx.x;
  const int lane = tid & 63, wave = tid >> 6;
  const int l16 = lane & 15, lhi = lane >> 4;
  const int nbn = N >> 7;
  const int bm = blockIdx.x / nbn, bn = blockIdx.x - bm * nbn;
  const int m0 = bm << 7, n0 = bn << 7;
  const int wm = (wave >> 1) << 6, wn = (wave & 1) << 6;
  f32x4 acc[4][4] = {};
  for (int k0 = 0; k0 < K; k0 += 64) {
#pragma unroll
    for (int it = 0; it < 4; ++it) {
      int slot = it * 256 + tid;
      int row = slot >> 3, col = (slot & 7) << 3;
      GLDS16(A + (size_t)(m0 + row) * K + k0 + col, As + (it * 256 + wave * 64) * 8);
      GLDS16(B + (size_t)(n0 + row) * K + k0 + col, Bs + (it * 256 + wave * 64) * 8);
    }
    __syncthreads();
#pragma unroll
    for (int ks = 0; ks < 2; ++ks) {
      bf16x8 a[4], b[4];
#pragma unroll
      for (int i = 0; i < 4; ++i) {
        a[i] = *(const bf16x8*)(As + (wm + i * 16 + l16) * 64 + ks * 32 + lhi * 8);
        b[i] = *(const bf16x8*)(Bs + (wn + i * 16 + l16) * 64 + ks * 32 + lhi * 8);
      }
#pragma unroll
      for (int i = 0; i < 4; ++i)
#pragma unroll
        for (int j = 0; j < 4; ++j)
          acc[i][j] = __builtin_amdgcn_mfma_f32_16x16x32_bf16(a[i], b[j], acc[i][j], 0, 0, 0);
    }
    __syncthreads();
  }
#pragma unroll
  for (int i = 0; i < 4; ++i)
#pragma unroll
    for (int j = 0; j < 4; ++j) {
      int col = n0 + wn + j * 16 + l16;
      int h = col / 192;           // magic-mul
      int jc = col - h * 192;
      int row0 = m0 + wm + i * 16 + lhi * 4;
      if (jc < 64) {  // K content column
#pragma unroll
        for (int r = 0; r < 4; ++r)
          kvfull[(size_t)(row0 + r) * 3072 + col] = f2bf(acc[i][j][r]);
      } else {        // V column -> transposed store (4 consecutive t = 8B)
        int d = jc - 64;
        int b = row0 >> 11, t0 = row0 & 2047;
        u16x4 pk;
#pragma unroll
        for (int r = 0; r < 4; ++r) pk[r] = f2bf(acc[i][j][r]);
        *(u16x4*)(VT + ((size_t)((b * 16 + h) * 128 + d)) * 2048 + t0) = pk;
      }
    }
}

// ---------------- fused RMS norms: q (1536) + kv (512) + RoPE of shared k_rope ----------------
__global__ __launch_bounds__(256) void rms_fused(const unsigned short* __restrict__ qkva,
                                                 const float* __restrict__ qw,
                                                 const float* __restrict__ kvw,
                                                 unsigned short* __restrict__ q_c,
                                                 unsigned short* __restrict__ kv_c,
                                                 unsigned short* __restrict__ krope) {
  const int row = blockIdx.x, tid = threadIdx.x;
  const unsigned short* p = qkva + (size_t)row * 2176;
  float fq[8];
  float ssq = 0.f;
  const bool act = tid < 192;
  if (act) {
    u16x8 v = *(const u16x8*)(p + tid * 8);
#pragma unroll
    for (int j = 0; j < 8; ++j) { fq[j] = bf2f(v[j]); ssq += fq[j] * fq[j]; }
  }
  float f0 = bf2f(p[1536 + tid * 2]), f1 = bf2f(p[1536 + tid * 2 + 1]);
  float sskv = f0 * f0 + f1 * f1;
#pragma unroll
  for (int m = 1; m <= 32; m <<= 1) {
    ssq += __shfl_xor(ssq, m);
    sskv += __shfl_xor(sskv, m);
  }
  __shared__ float rq[4], rkv[4];
  if ((tid & 63) == 0) { rq[tid >> 6] = ssq; rkv[tid >> 6] = sskv; }
  __syncthreads();
  float rstdq = rsqrtf((rq[0] + rq[1] + rq[2] + rq[3]) * (1.f / 1536.f) + 1e-6f);
  float rstdkv = rsqrtf((rkv[0] + rkv[1] + rkv[2] + rkv[3]) * (1.f / 512.f) + 1e-6f);
  if (act) {
    u16x8 o;
#pragma unroll
    for (int j = 0; j < 8; ++j) o[j] = f2bf(fq[j] * rstdq * qw[tid * 8 + j]);
    *(u16x8*)(q_c + (size_t)row * 1536 + tid * 8) = o;
  }
  kv_c[(size_t)row * 512 + tid * 2]     = f2bf(f0 * rstdkv * kvw[tid * 2]);
  kv_c[(size_t)row * 512 + tid * 2 + 1] = f2bf(f1 * rstdkv * kvw[tid * 2 + 1]);
  if (tid < 32) {
    int j = tid;
    float xr = bf2f(p[2048 + 2 * j]), xi = bf2f(p[2048 + 2 * j + 1]);
    int t = row & 2047;
    float ang = (float)t * powf(10000.f, -(float)j * (1.f / 32.f));
    float c = cosf(ang), s = sinf(ang);
    krope[(size_t)row * 64 + 2 * j]     = f2bf(xr * c - xi * s);
    krope[(size_t)row * 64 + 2 * j + 1] = f2bf(xr * s + xi * c);
  }
}

// ---------------- causal flash attention, high-occupancy ----------------
// 1024 blocks: one 64-row q-block each; 4 waves x 16 q-rows. Single-buffered K/V
// (32KB LDS) + __launch_bounds__(256,4) -> 4 independent blocks/CU; TLP (not intra-
// block prefetch) hides staging latency. Swapped-QK^T, in-register softmax (exp2,
// defer-max), P in registers via cvt_pk+permlane, O^T = mfma(V^T, P).
// Block mapping: per-XCD chunks; s and 31-s interleaved so concurrent blocks on a
// CU have ~constant total work; the 4 (b,h) groups per XCD keep K/V in that L2.
__global__ __launch_bounds__(256, 4) void flash_attn(const unsigned short* __restrict__ qfull,
                                                     const unsigned short* __restrict__ kvfull, // [4096][3072]
                                                     const unsigned short* __restrict__ krope,  // [4096][64]
                                                     const unsigned short* __restrict__ Vt,     // [B][H][128][2048]
                                                     unsigned short* __restrict__ out) {
  const int tid = threadIdx.x, lane = tid & 63, wave = tid >> 6;
  const int l16 = lane & 15, lhi = lane >> 4;
  const int bid = blockIdx.x;
  const int xcd = bid & 7, Lb = bid >> 3;      // Lb 0..127 within XCD chunk
  const int bhl = Lb >> 5, cL = Lb & 31;
  const int s = (bhl & 1) ? (31 - cL) : cL;    // alternate s / 31-s per dispatch round
  const int bh = xcd * 4 + bhl;
  const int h = bh & 15, b = bh >> 4;
  __shared__ __align__(16) unsigned short Ks[64 * 128];
  __shared__ __align__(16) unsigned short Vs[64 * 128];

  // --- Q fragment: 16 q-rows (this wave), RoPE on d>=64, fold (1/8)*log2(e) ---
  const float QSCALE = 0.125f * 1.44269504089f;
  bf16x8 qf[4];
  f32x4 o_acc[8] = {};
  const int qg = s * 64 + wave * 16 + l16;
  {
    const unsigned short* qrow = qfull + (size_t)(b * 2048 + qg) * 2048 + h * 128;
#pragma unroll
    for (int ks = 0; ks < 4; ++ks) {
      u16x8 raw = *(const u16x8*)(qrow + ks * 32 + lhi * 8);
      float f[8];
#pragma unroll
      for (int j = 0; j < 8; ++j) f[j] = bf2f(raw[j]);
      if (ks >= 2) {
#pragma unroll
        for (int pp = 0; pp < 4; ++pp) {
          int d = ks * 32 + lhi * 8 + 2 * pp;
          int jl = (d - 64) >> 1;
          float ang = (float)qg * powf(10000.f, -(float)jl * (1.f / 32.f));
          float co = cosf(ang), si = sinf(ang);
          float xr = f[2 * pp], xi = f[2 * pp + 1];
          f[2 * pp] = xr * co - xi * si;
          f[2 * pp + 1] = xr * si + xi * co;
        }
      }
      bf16x8 fr;
#pragma unroll
      for (int j = 0; j < 8; ++j) fr[j] = (short)f2bf(f[j] * QSCALE);
      qf[ks] = fr;
    }
  }
  float m_run = -1e30f, l_run = 0.f;

  const int bT = b * 2048;
  const unsigned short* Vbh = Vt + (size_t)(b * 16 + h) * 128 * 2048;

  for (int kt = 0; kt <= s; ++kt) {
    // --- stage K (content from kvfull + rope from krope) and V^T; linear LDS dest,
    //     inverse-XOR-swizzled per-lane global source ---
#pragma unroll
    for (int it = 0; it < 4; ++it) {
      int Lo = it * 4096 + wave * 1024 + lane * 16;
      int r = Lo >> 8;
      int w = (Lo & 255) ^ ((r & 7) << 4);
      int cc = w >> 1;
      int tl = bT + kt * 64 + r;
      const unsigned short* src = (cc < 64) ? kvfull + (size_t)tl * 3072 + h * 192 + cc
                                            : krope + (size_t)tl * 64 + (cc - 64);
      GLDS16(src, Ks + ((it * 4096 + wave * 1024) >> 1));
    }
#pragma unroll
    for (int it = 0; it < 4; ++it) {
      int Lo = it * 4096 + wave * 1024 + lane * 16;
      int d = Lo >> 7;
      int w = (Lo & 127) ^ ((d & 7) << 4);
      GLDS16(Vbh + (size_t)d * 2048 + kt * 64 + (w >> 1), Vs + ((it * 4096 + wave * 1024) >> 1));
    }
    __syncthreads();  // vmcnt drain: staged tile visible

    // --- S^T = K @ Q^T (lane: col = q = l16; rows k = nt*16 + lhi*4 + r) ---
    f32x4 st[4] = {};
    __builtin_amdgcn_s_setprio(1);
#pragma unroll
    for (int ks = 0; ks < 4; ++ks) {
      bf16x8 kf;
#pragma unroll
      for (int nt = 0; nt < 4; ++nt) {
        int row = nt * 16 + l16;
        int byteoff = row * 256 + ((ks * 64 + lhi * 16) ^ ((l16 & 7) << 4));
        kf = *(const bf16x8*)((const char*)Ks + byteoff);
        st[nt] = __builtin_amdgcn_mfma_f32_16x16x32_bf16(kf, qf[ks], st[nt], 0, 0, 0);
      }
    }
    __builtin_amdgcn_s_setprio(0);

    // --- softmax (exp2 domain, defer-max), P fragments in registers ---
    if (kt == s) {  // diagonal: causal mask
#pragma unroll
      for (int nt = 0; nt < 4; ++nt)
#pragma unroll
        for (int r = 0; r < 4; ++r) {
          int kg = kt * 64 + nt * 16 + lhi * 4 + r;
          st[nt][r] = (kg <= qg) ? st[nt][r] : -1e30f;
        }
    }
    float mx = -1e30f;
#pragma unroll
    for (int nt = 0; nt < 4; ++nt)
#pragma unroll
      for (int r = 0; r < 4; ++r) mx = fmaxf(mx, st[nt][r]);
    mx = fmaxf(mx, __shfl_xor(mx, 16));
    mx = fmaxf(mx, __shfl_xor(mx, 32));
    if (__ballot(mx > m_run + 8.f)) {
      float mnew = fmaxf(m_run, mx);
      float sc = exp2f(m_run - mnew);
      m_run = mnew;
      l_run *= sc;
#pragma unroll
      for (int dt = 0; dt < 8; ++dt) o_acc[dt] *= sc;
    }
    const float mcur = m_run;
    float sum = 0.f;
#pragma unroll
    for (int nt = 0; nt < 4; ++nt)
#pragma unroll
      for (int r = 0; r < 4; ++r) {
        float p = exp2f(st[nt][r] - mcur);
        st[nt][r] = p;
        sum += p;
      }
    sum += __shfl_xor(sum, 16);
    sum += __shfl_xor(sum, 32);
    l_run += sum;
    bf16x8 pw[2];
    {
      unsigned pk01[4], pk23[4];
#pragma unroll
      for (int nt = 0; nt < 4; ++nt) {
        pk01[nt] = cvtpk(st[nt][0], st[nt][1]);
        pk23[nt] = cvtpk(st[nt][2], st[nt][3]);
      }
#pragma unroll
      for (int k2 = 0; k2 < 2; ++k2) {
        unsigned a0 = pk01[2 * k2], b0 = pk01[2 * k2 + 1];
        unsigned a1 = pk23[2 * k2], b1 = pk23[2 * k2 + 1];
        p32swap(a0, b0); p16swap(a0, b0);
        p32swap(a1, b1); p16swap(a1, b1);
        u32x4 t4 = {a0, a1, b0, b1};
        pw[k2] = *(bf16x8*)&t4;
      }
    }

    // --- O^T += V^T @ P (lane: col = q = l16; rows d) ---
    __builtin_amdgcn_s_setprio(1);
#pragma unroll
    for (int k2 = 0; k2 < 2; ++k2)
#pragma unroll
      for (int dt = 0; dt < 8; ++dt) {
        int row = dt * 16 + l16;
        int byteoff = row * 128 + ((k2 * 64 + lhi * 16) ^ ((l16 & 7) << 4));
        bf16x8 vf = *(const bf16x8*)((const char*)Vs + byteoff);
        o_acc[dt] = __builtin_amdgcn_mfma_f32_16x16x32_bf16(vf, pw[k2], o_acc[dt], 0, 0, 0);
      }
    __builtin_amdgcn_s_setprio(0);

    __syncthreads();  // all reads of Ks/Vs done before next stage overwrites
  }

  // --- epilogue: lane holds O^T[d = dt*16+lhi*4+r][q=l16] ---
  {
    float inv = 1.0f / l_run;
    unsigned short* orow = out + (size_t)(b * 2048 + qg) * 2048 + h * 128;
#pragma unroll
    for (int dt = 0; dt < 8; ++dt) {
      unsigned w01 = cvtpk(o_acc[dt][0] * inv, o_acc[dt][1] * inv);
      unsigned w23 = cvtpk(o_acc[dt][2] * inv, o_acc[dt][3] * inv);
      u32x2 st2 = {w01, w23};
      *(u32x2*)(orow + dt * 16 + lhi * 4) = st2;
    }
  }
}

// =====================================================================================
extern "C" void kernel_launch(void* const* d_in, const int* in_sizes, int n_in,
                              void* d_out, int out_size, void* d_ws, size_t ws_size,
                              hipStream_t stream) {
  (void)in_sizes; (void)n_in; (void)out_size; (void)ws_size;
  const float* x      = (const float*)d_in[0];
  const float* w_qa   = (const float*)d_in[2];
  const float* qa_nw  = (const float*)d_in[3];
  const float* w_qb   = (const float*)d_in[4];
  const float* w_kva  = (const float*)d_in[5];
  const float* kva_nw = (const float*)d_in[6];
  const float* w_kvb  = (const float*)d_in[7];
  const float* w_o    = (const float*)d_in[8];
  float* out = (float*)d_out;
  char* ws = (char*)d_ws;

  unsigned short* xb     = (unsigned short*)(ws + 0);
  unsigned short* wqkva  = (unsigned short*)(ws + 16777216);   // [2176][2048]
  unsigned short* wqbb   = (unsigned short*)(ws + 25690112);
  unsigned short* wkvbb  = (unsigned short*)(ws + 31981568);
  unsigned short* wob    = (unsigned short*)(ws + 35127296);
  unsigned short* qkva   = (unsigned short*)(ws + 43515904);   // [4096][2176]
  unsigned short* qfull  = (unsigned short*)(ws + 43515904);   // alias (qkva dead after rms)
  unsigned short* q_c    = (unsigned short*)(ws + 61341696);   // [4096][1536]
  unsigned short* kv_c   = (unsigned short*)(ws + 73924608);   // [4096][512]
  unsigned short* krope  = (unsigned short*)(ws + 78118912);   // [4096][64]
  unsigned short* attno  = (unsigned short*)(ws + 61341696);   // alias (q_c+kv_c dead)
  unsigned short* Vattn  = (unsigned short*)(ws + 78643200);   // [B][H][128][2048]
  unsigned short* kvfull = (unsigned short*)d_out;             // scratch in d_out (k cols only)

  convert_all<<<21248, 256, 0, stream>>>(x, w_qa, w_kva, w_qb, w_kvb, w_o,
                                         xb, wqkva, wqbb, wkvbb, wob);

  // fused low-rank projections: [4096][2176] = xb @ [w_qa ++ w_kva]^T
  gemm_bt<unsigned short><<<32 * 17, 256, 0, stream>>>(xb, wqkva, qkva, 4096, 2176, 2048);

  rms_fused<<<4096, 256, 0, stream>>>(qkva, qa_nw, kva_nw, q_c, kv_c, krope);

  gemm_bt<unsigned short><<<32 * 16, 256, 0, stream>>>(q_c, wqbb, qfull, 4096, 2048, 1536);
  gemm_kvb<<<32 * 24, 256, 0, stream>>>(kv_c, wkvbb, kvfull, Vattn);

  flash_attn<<<1024, 256, 0, stream>>>(qfull, kvfull, krope, Vattn, attno);

  gemm_bt<float><<<32 * 16, 256, 0, stream>>>(attno, wob, out, 4096, 2048, 2048);
}